// Round 7
// baseline (383.586 us; speedup 1.0000x reference)
//
#include <hip/hip_runtime.h>

typedef _Float16 f16;
typedef __attribute__((ext_vector_type(2))) _Float16 f16x2;
typedef __attribute__((ext_vector_type(4))) _Float16 f16x4;
typedef __attribute__((ext_vector_type(8))) _Float16 f16x8;
typedef __attribute__((ext_vector_type(4))) float fvec4;
typedef __attribute__((ext_vector_type(4))) float f32x4;
typedef __attribute__((ext_vector_type(16))) float f32x16;
typedef __attribute__((ext_vector_type(4))) unsigned int uint4v;

#define NKEY 784
#define NKEYP 800
#define NQ 196
#define NQP 224

static __device__ __forceinline__ f32x4 mfma16(f16x8 a, f16x8 b, f32x4 c) {
    return __builtin_amdgcn_mfma_f32_16x16x32_f16(a, b, c, 0, 0, 0);
}
static __device__ __forceinline__ f32x16 mfma32(f16x8 a, f16x8 b, f32x16 c) {
    return __builtin_amdgcn_mfma_f32_32x32x16_f16(a, b, c, 0, 0, 0);
}
static __device__ __forceinline__ unsigned pk2(float a, float b) {
    f16x2 t; t[0] = (_Float16)a; t[1] = (_Float16)b;
    return __builtin_bit_cast(unsigned, t);
}
static __device__ __forceinline__ f32x16 z16() {
    f32x16 v;
#pragma unroll
    for (int i = 0; i < 16; ++i) v[i] = 0.f;
    return v;
}

// ---------------- prep: fold BN into scale/shift (all three BNs) ----------------
__global__ void prep_scales_all(const float* __restrict__ kg, const float* __restrict__ kb,
                                const float* __restrict__ km, const float* __restrict__ kvv,
                                const float* __restrict__ qg, const float* __restrict__ qb,
                                const float* __restrict__ qm, const float* __restrict__ qv,
                                const float* __restrict__ pg, const float* __restrict__ pb,
                                const float* __restrict__ pm, const float* __restrict__ pv,
                                float* __restrict__ sb) {
    int i = blockIdx.x * 256 + threadIdx.x;
    if (i < 640) {
        float s = kg[i] * rsqrtf(kvv[i] + 1e-5f);
        sb[i] = s; sb[640 + i] = kb[i] - km[i] * s;
    } else if (i < 768) {
        int j = i - 640;
        float s = qg[j] * rsqrtf(qv[j] + 1e-5f);
        sb[1280 + j] = s; sb[1408 + j] = qb[j] - qm[j] * s;
    } else if (i < 1152) {
        int j = i - 768;
        float s = pg[j] * rsqrtf(pv[j] + 1e-5f);
        sb[1536 + j] = s; sb[1920 + j] = pb[j] - pm[j] * s;
    }
}

// ---------------- prep: convert weights to f16, k-major fragment layout ----------------
// Wt element (n, k) at [(k/8)*NT + n]*8 + (k%8)  (per weight matrix)
__global__ void conv_w(const float* __restrict__ wkv, const float* __restrict__ wq,
                       const float* __restrict__ wp, f16* __restrict__ out) {
    int i = blockIdx.x * 256 + threadIdx.x;   // 49152 threads = 20480 + 4096 + 24576
    const float* src;
    f16* dst;
    int kc, n, K;
    if (i < 20480)      { int j = i;         kc = j / 640, n = j - kc * 640; src = wkv; dst = out + (size_t)j * 8;            K = 256; }
    else if (i < 24576) { int j = i - 20480; kc = j / 128, n = j - kc * 128; src = wq;  dst = out + 163840 + (size_t)j * 8;   K = 256; }
    else                { int j = i - 24576; kc = j / 384, n = j - kc * 384; src = wp;  dst = out + 196608 + (size_t)j * 8;   K = 512; }
    const float* s = src + (size_t)n * K + kc * 8;
    fvec4 v0 = *(const fvec4*)s;
    fvec4 v1 = *(const fvec4*)(s + 4);
    f16x8 h;
    h[0] = (f16)v0[0]; h[1] = (f16)v0[1]; h[2] = (f16)v0[2]; h[3] = (f16)v0[3];
    h[4] = (f16)v1[0]; h[5] = (f16)v1[1]; h[6] = (f16)v1[2]; h[7] = (f16)v1[3];
    *(f16x8*)dst = h;
}

// ---------------- prep: gather bias f16 [h][q(224)][key(800)] ----------------
__global__ void prep_bias(const float* __restrict__ biases, const int* __restrict__ idxs,
                          f16* __restrict__ biasT, int n_off) {
    int tid = blockIdx.x * 256 + threadIdx.x;   // 8*224*800
    int h = tid / (NQP * NKEYP);
    int rem = tid - h * (NQP * NKEYP);
    int q = rem / NKEYP;
    int key = rem - q * NKEYP;
    float v = 0.f;
    if (q < NQ && key < NKEY) v = biases[h * n_off + idxs[q * NKEY + key]];
    biasT[tid] = (f16)v;
}

// ---------------- register-A GEMM, k-major W ----------------
// MODE 0: kv  : MF=2 (wave=32 rows), NCP=5, grid (784, 2)
//               A f32 [100352][256] -> K f16 [1024][800][16]
//                                      + V f16 [1024][25][64][32]  (keyblock-tiled)
// MODE 1: q   : MF=1, A f32 subsampled -> q f16 [1024][224][16]   (grid.y = 2)
// MODE 2: proj: MF=1, A f16 [25088][512] -> out f32 [25088][384]  (grid.y = 2)
template <int MODE>
__global__ __launch_bounds__(256) void gemm_reg(const void* __restrict__ Ap,
                                                const f16* __restrict__ Wt,
                                                const float* __restrict__ sc,
                                                const float* __restrict__ sh,
                                                void* __restrict__ OutA,
                                                f16* __restrict__ OutV) {
    constexpr int K  = (MODE == 2) ? 512 : 256;
    constexpr int KS = K / 32;
    constexpr int MF = (MODE == 0) ? 2 : 1;    // rows per wave = 16*MF
    constexpr int NT = (MODE == 0) ? 640 : (MODE == 1 ? 128 : 384);
    constexpr int NCP = (MODE == 0) ? 5 : (MODE == 1 ? 1 : 3);   // chunks per block

    const int t = threadIdx.x;
    const int lane = t & 63, wid = t >> 6;
    const int fr = lane & 15, kg = lane >> 4;
    const int m0 = blockIdx.x * (64 * MF);
    const int nb0 = blockIdx.y * (NCP * 64);
    const int wrow0 = m0 + wid * (16 * MF);

    // ---- A fragments into registers ----
    f16x8 af[MF][KS];
#pragma unroll
    for (int mf = 0; mf < MF; ++mf) {
        const int mrow = wrow0 + mf * 16 + fr;
        size_t arow;
        if constexpr (MODE == 1) {
            int b = mrow / 196, nn = mrow - b * 196;
            arow = (size_t)b * 784 + (nn / 14) * 56 + (nn % 14) * 2;
        } else {
            arow = (size_t)mrow;
        }
#pragma unroll
        for (int ks = 0; ks < KS; ++ks) {
            if constexpr (MODE == 2) {
                af[mf][ks] = *(const f16x8*)((const f16*)Ap + arow * K + ks * 32 + kg * 8);
            } else {
                const float* a = (const float*)Ap + arow * 256 + ks * 32 + kg * 8;
                fvec4 v0 = *(const fvec4*)a;
                fvec4 v1 = *(const fvec4*)(a + 4);
                f16x8 hv;
                hv[0] = (f16)v0[0]; hv[1] = (f16)v0[1]; hv[2] = (f16)v0[2]; hv[3] = (f16)v0[3];
                hv[4] = (f16)v1[0]; hv[5] = (f16)v1[1]; hv[6] = (f16)v1[2]; hv[7] = (f16)v1[3];
                af[mf][ks] = hv;
            }
        }
    }

    const int rg = kg * 4;
    for (int c = 0; c < NCP; ++c) {
        const int n0c = nb0 + c * 64;
        f32x4 acc[MF][4];
#pragma unroll
        for (int i = 0; i < MF; ++i)
#pragma unroll
            for (int j = 0; j < 4; ++j) acc[i][j] = (f32x4){0.f, 0.f, 0.f, 0.f};

#pragma unroll
        for (int ks = 0; ks < KS; ++ks) {
            f16x8 bfr[4];
#pragma unroll
            for (int nf = 0; nf < 4; ++nf)
                bfr[nf] = *(const f16x8*)(Wt + ((size_t)(ks * 4 + kg) * NT + n0c + nf * 16 + fr) * 8);
#pragma unroll
            for (int mf = 0; mf < MF; ++mf)
#pragma unroll
                for (int nf = 0; nf < 4; ++nf)
                    acc[mf][nf] = mfma16(af[mf][ks], bfr[nf], acc[mf][nf]);
        }

        // ---- epilogue ----
#pragma unroll
        for (int mf = 0; mf < MF; ++mf) {
            const int mbase = wrow0 + mf * 16 + rg;   // 4 consecutive output rows
#pragma unroll
            for (int nf = 0; nf < 4; ++nf) {
                const int n = n0c + nf * 16 + fr;
                const float scn = sc[n], shn = sh[n];
                if constexpr (MODE == 0) {
                    const int b = mbase / 784;
                    const int nn = mbase - b * 784;      // %4==0, 4-row group in one b
                    const int hd = n / 80;
                    const int cc = n - hd * 80;
                    const size_t bh = (size_t)(b * 8 + hd);
                    if (cc < 16) {
#pragma unroll
                        for (int r = 0; r < 4; ++r) {
                            float y = acc[mf][nf][r] * scn + shn;
                            ((f16*)OutA)[(bh * NKEYP + nn + r) * 16 + cc] = (f16)y;
                        }
                    } else {
                        // keyblock-tiled V: [bh][kb][d(64)][key%32] -> page-local writes
                        const int kbk = nn >> 5, off = nn & 31;
                        f16x4 pv;
#pragma unroll
                        for (int r = 0; r < 4; ++r) pv[r] = (f16)(acc[mf][nf][r] * scn + shn);
                        *(f16x4*)(OutV + ((bh * 25 + kbk) * 64 + (cc - 16)) * 32 + off) = pv;
                    }
                } else if constexpr (MODE == 1) {
                    const int b = mbase / 196;
                    const int nn = mbase - b * 196;
                    const int hd = n >> 4, cc = n & 15;
                    const size_t bh = (size_t)(b * 8 + hd);
#pragma unroll
                    for (int r = 0; r < 4; ++r) {
                        float y = acc[mf][nf][r] * scn + shn;
                        ((f16*)OutA)[(bh * NQP + nn + r) * 16 + cc] = (f16)y;
                    }
                } else {
#pragma unroll
                    for (int r = 0; r < 4; ++r) {
                        float y = acc[mf][nf][r] * scn + shn;
                        ((float*)OutA)[(size_t)(mbase + r) * 384 + n] = y;
                    }
                }
            }
        }
    }
}

// ---------------- fused attention: block = (b,h), 7 waves = 7 q-tiles ----------------
// V layout: [bh][kb=key/32][d(64)][key%32] — fragment load stays one f16x8.
__global__ __launch_bounds__(448) void attn_fused(const f16* __restrict__ kb,
                                                  const f16* __restrict__ vtb,
                                                  const f16* __restrict__ qw,
                                                  const f16* __restrict__ biasT,
                                                  f16* __restrict__ ao) {
    const int bh = blockIdx.x;
    const int b = bh >> 3, h = bh & 7;
    const int wid = threadIdx.x >> 6;      // q-tile 0..6
    const int lane = threadIdx.x & 63;
    const int l31 = lane & 31;
    const int hh = lane >> 5;
    const int q0 = wid * 32;

    const f16* kp = kb + (size_t)bh * (NKEYP * 16);
    const f16* vp = vtb + (size_t)bh * (25 * 64 * 32) + l31 * 32;
    const f16x8 bq = *(const f16x8*)(qw + ((size_t)bh * NQP + q0 + l31) * 16 + hh * 8);
    const f16* bbq = biasT + ((size_t)h * NQP + (q0 + l31)) * NKEYP;

    float mrun = -1e30f;
    float lsum = 0.f;
    f32x16 o0 = z16(), o1 = z16();

    for (int key0 = 0; key0 < NKEY; key0 += 32) {
        f16x8 ak = *(const f16x8*)(kp + (size_t)(key0 + l31) * 16 + hh * 8);
        f32x16 s = mfma32(ak, bq, z16());
        const bool tail = (key0 + 32) > NKEY;
        f16x4 bw[4];
#pragma unroll
        for (int g = 0; g < 4; ++g)
            bw[g] = *(const f16x4*)(bbq + key0 + g * 8 + hh * 4);
        float p[16];
        float cmax = -3.0e38f;
#pragma unroll
        for (int r = 0; r < 16; ++r) {
            const int cr = (r & 3) + ((r >> 2) << 3) + (hh << 2);
            float sv = s[r] * 0.25f + (float)bw[r >> 2][r & 3];
            if (tail && (key0 + cr) >= NKEY) sv = -1e30f;
            p[r] = sv;
            cmax = fmaxf(cmax, sv);
        }
        cmax = fmaxf(cmax, __shfl_xor(cmax, 32));
        if (__any(cmax > mrun + 8.f)) {          // defer-max
            float mnew = fmaxf(mrun, cmax);
            float f = __expf(mrun - mnew);
            mrun = mnew;
            lsum *= f;
#pragma unroll
            for (int r = 0; r < 16; ++r) {
                const int cr = (r & 3) + ((r >> 2) << 3) + (hh << 2);
                float fr2 = __shfl(f, cr);
                o0[r] *= fr2;
                o1[r] *= fr2;
            }
        }
        float psum = 0.f;
#pragma unroll
        for (int r = 0; r < 16; ++r) {
            p[r] = __expf(p[r] - mrun);
            psum += p[r];
        }
        lsum += psum;
        unsigned g0l = pk2(p[0], p[1]),   g0h = pk2(p[2], p[3]);
        unsigned g1l = pk2(p[4], p[5]),   g1h = pk2(p[6], p[7]);
        unsigned g2l = pk2(p[8], p[9]),   g2h = pk2(p[10], p[11]);
        unsigned g3l = pk2(p[12], p[13]), g3h = pk2(p[14], p[15]);
        __builtin_amdgcn_s_setprio(1);
        const f16* vkb = vp + (key0 >> 5) * (64 * 32);
#pragma unroll
        for (int sH = 0; sH < 2; ++sH) {
            unsigned self_lo = sH ? (hh ? g3l : g2l) : (hh ? g1l : g0l);
            unsigned self_hi = sH ? (hh ? g3h : g2h) : (hh ? g1h : g0h);
            unsigned tx_lo   = sH ? (hh ? g2l : g3l) : (hh ? g0l : g1l);
            unsigned tx_hi   = sH ? (hh ? g2h : g3h) : (hh ? g0h : g1h);
            unsigned rx_lo = __shfl_xor(tx_lo, 32);
            unsigned rx_hi = __shfl_xor(tx_hi, 32);
            uint4v w;
            w[0] = hh ? rx_lo : self_lo;
            w[1] = hh ? rx_hi : self_hi;
            w[2] = hh ? self_lo : rx_lo;
            w[3] = hh ? self_hi : rx_hi;
            f16x8 pa = __builtin_bit_cast(f16x8, w);
            const f16* vrow = vkb + sH * 16 + hh * 8;
            f16x8 bv0 = *(const f16x8*)(vrow);
            f16x8 bv1 = *(const f16x8*)(vrow + 32 * 32);
            o0 = mfma32(pa, bv0, o0);
            o1 = mfma32(pa, bv1, o1);
        }
        __builtin_amdgcn_s_setprio(0);
    }
    lsum += __shfl_xor(lsum, 32);
    const float inv = 1.0f / lsum;
#pragma unroll
    for (int r = 0; r < 16; ++r) {
        const int cr = (r & 3) + ((r >> 2) << 3) + (hh << 2);
        const float iq = __shfl(inv, cr);
        const int qg = q0 + cr;
        if (qg < NQ) {
            float v0 = o0[r] * iq, v1 = o1[r] * iq;
            float h0 = v0 * fminf(fmaxf(v0 + 3.f, 0.f), 6.f) * (1.f / 6.f);
            float h1 = v1 * fminf(fmaxf(v1 + 3.f, 0.f), 6.f) * (1.f / 6.f);
            f16* dst = ao + ((size_t)b * NQ + qg) * 512 + h * 64 + l31;
            dst[0] = (f16)h0;
            dst[32] = (f16)h1;
        }
    }
}

// ---------------- launch ----------------
extern "C" void kernel_launch(void* const* d_in, const int* in_sizes, int n_in,
                              void* d_out, int out_size, void* d_ws, size_t ws_size,
                              hipStream_t stream) {
    (void)n_in; (void)out_size; (void)ws_size;
    const float* hidden = (const float*)d_in[0];
    const float* w_kv   = (const float*)d_in[1];
    const float* w_q    = (const float*)d_in[6];
    const float* w_p    = (const float*)d_in[11];
    const float* biases = (const float*)d_in[16];
    const int*   idxs   = (const int*)d_in[17];
    const int n_off = in_sizes[16] / 8;

    char* ws = (char*)d_ws;
    const size_t OFF_K  = 0;                       // 26,214,400
    const size_t OFF_V  = 26214400;                // 104,857,600
    const size_t OFF_Q  = 131072000;               //   7,340,032
    const size_t OFF_AO = 138412032;               //  25,690,112
    const size_t OFF_BT = 164102144;               //   2,867,200
    const size_t OFF_W  = 166969344;               //     786,432
    const size_t OFF_SC = 167755776;               //       9,216
    f16*   kbuf  = (f16*)(ws + OFF_K);
    f16*   vbuf  = (f16*)(ws + OFF_V);
    f16*   qbuf  = (f16*)(ws + OFF_Q);
    f16*   aobuf = (f16*)(ws + OFF_AO);
    f16*   btbuf = (f16*)(ws + OFF_BT);
    f16*   wf16  = (f16*)(ws + OFF_W);
    float* scbuf = (float*)(ws + OFF_SC);

    prep_scales_all<<<5, 256, 0, stream>>>(
        (const float*)d_in[2], (const float*)d_in[3], (const float*)d_in[4], (const float*)d_in[5],
        (const float*)d_in[7], (const float*)d_in[8], (const float*)d_in[9], (const float*)d_in[10],
        (const float*)d_in[12], (const float*)d_in[13], (const float*)d_in[14], (const float*)d_in[15],
        scbuf);
    conv_w<<<192, 256, 0, stream>>>(w_kv, w_q, w_p, wf16);
    prep_bias<<<5600, 256, 0, stream>>>(biases, idxs, btbuf, n_off);
    hipMemsetAsync(qbuf, 0, (size_t)1024 * NQP * 16 * 2, stream);  // zero q pad rows
    gemm_reg<0><<<dim3(784, 2), 256, 0, stream>>>(hidden, wf16, scbuf, scbuf + 640, kbuf, vbuf);
    gemm_reg<1><<<dim3(392, 2), 256, 0, stream>>>(hidden, wf16 + 163840, scbuf + 1280, scbuf + 1408, qbuf, nullptr);
    attn_fused<<<1024, 448, 0, stream>>>(kbuf, vbuf, qbuf, btbuf, aobuf);
    gemm_reg<2><<<dim3(392, 2), 256, 0, stream>>>(aobuf, wf16 + 196608, scbuf + 1536, scbuf + 1920, d_out, nullptr);
}

// Round 8
// 243.396 us; speedup vs baseline: 1.5760x; 1.5760x over previous
//
#include <hip/hip_runtime.h>

typedef _Float16 f16;
typedef __attribute__((ext_vector_type(2))) _Float16 f16x2;
typedef __attribute__((ext_vector_type(4))) _Float16 f16x4;
typedef __attribute__((ext_vector_type(8))) _Float16 f16x8;
typedef __attribute__((ext_vector_type(4))) float fvec4;
typedef __attribute__((ext_vector_type(4))) float f32x4;
typedef __attribute__((ext_vector_type(16))) float f32x16;
typedef __attribute__((ext_vector_type(4))) unsigned int uint4v;

#define NKEY 784
#define NKEYP 800
#define NQ 196
#define NQP 224

static __device__ __forceinline__ f32x4 mfma16(f16x8 a, f16x8 b, f32x4 c) {
    return __builtin_amdgcn_mfma_f32_16x16x32_f16(a, b, c, 0, 0, 0);
}
static __device__ __forceinline__ f32x16 mfma32(f16x8 a, f16x8 b, f32x16 c) {
    return __builtin_amdgcn_mfma_f32_32x32x16_f16(a, b, c, 0, 0, 0);
}
static __device__ __forceinline__ unsigned pk2(float a, float b) {
    f16x2 t; t[0] = (_Float16)a; t[1] = (_Float16)b;
    return __builtin_bit_cast(unsigned, t);
}
static __device__ __forceinline__ f32x16 z16() {
    f32x16 v;
#pragma unroll
    for (int i = 0; i < 16; ++i) v[i] = 0.f;
    return v;
}

// ---------------- prep: fold BN into scale/shift (all three BNs) ----------------
__global__ void prep_scales_all(const float* __restrict__ kg, const float* __restrict__ kb,
                                const float* __restrict__ km, const float* __restrict__ kvv,
                                const float* __restrict__ qg, const float* __restrict__ qb,
                                const float* __restrict__ qm, const float* __restrict__ qv,
                                const float* __restrict__ pg, const float* __restrict__ pb,
                                const float* __restrict__ pm, const float* __restrict__ pv,
                                float* __restrict__ sb) {
    int i = blockIdx.x * 256 + threadIdx.x;
    if (i < 640) {
        float s = kg[i] * rsqrtf(kvv[i] + 1e-5f);
        sb[i] = s; sb[640 + i] = kb[i] - km[i] * s;
    } else if (i < 768) {
        int j = i - 640;
        float s = qg[j] * rsqrtf(qv[j] + 1e-5f);
        sb[1280 + j] = s; sb[1408 + j] = qb[j] - qm[j] * s;
    } else if (i < 1152) {
        int j = i - 768;
        float s = pg[j] * rsqrtf(pv[j] + 1e-5f);
        sb[1536 + j] = s; sb[1920 + j] = pb[j] - pm[j] * s;
    }
}

// ---------------- prep: convert weights to f16, k-major fragment layout ----------------
// Wt element (n, k) at [(k/8)*NT + n]*8 + (k%8)  (per weight matrix)
__global__ void conv_w(const float* __restrict__ wkv, const float* __restrict__ wq,
                       const float* __restrict__ wp, f16* __restrict__ out) {
    int i = blockIdx.x * 256 + threadIdx.x;   // 49152 threads = 20480 + 4096 + 24576
    const float* src;
    f16* dst;
    int kc, n, K;
    if (i < 20480)      { int j = i;         kc = j / 640, n = j - kc * 640; src = wkv; dst = out + (size_t)j * 8;            K = 256; }
    else if (i < 24576) { int j = i - 20480; kc = j / 128, n = j - kc * 128; src = wq;  dst = out + 163840 + (size_t)j * 8;   K = 256; }
    else                { int j = i - 24576; kc = j / 384, n = j - kc * 384; src = wp;  dst = out + 196608 + (size_t)j * 8;   K = 512; }
    const float* s = src + (size_t)n * K + kc * 8;
    fvec4 v0 = *(const fvec4*)s;
    fvec4 v1 = *(const fvec4*)(s + 4);
    f16x8 h;
    h[0] = (f16)v0[0]; h[1] = (f16)v0[1]; h[2] = (f16)v0[2]; h[3] = (f16)v0[3];
    h[4] = (f16)v1[0]; h[5] = (f16)v1[1]; h[6] = (f16)v1[2]; h[7] = (f16)v1[3];
    *(f16x8*)dst = h;
}

// ---------------- prep: gather bias f16 [h][q(224)][key(800)] ----------------
__global__ void prep_bias(const float* __restrict__ biases, const int* __restrict__ idxs,
                          f16* __restrict__ biasT, int n_off) {
    int tid = blockIdx.x * 256 + threadIdx.x;   // 8*224*800
    int h = tid / (NQP * NKEYP);
    int rem = tid - h * (NQP * NKEYP);
    int q = rem / NKEYP;
    int key = rem - q * NKEYP;
    float v = 0.f;
    if (q < NQ && key < NKEY) v = biases[h * n_off + idxs[q * NKEY + key]];
    biasT[tid] = (f16)v;
}

// ---------------- GEMM: A in registers (read once), W chunk in LDS (block-shared) ----------------
// Per chunk: block stages 32 KB of k-major W into LDS, all waves MFMA against it.
// B-fragment reads become ~12cy ds_read_b128 (uniform bank coverage) instead of ~250cy L2.
// MODE 0: kv  : 512thr/128rows, grid(784,2) : A f32 [100352][256] -> K f16 [1024][800][16]
//                                              + V f16 [1024][25][64][32]  (keyblock-tiled)
// MODE 1: q   : 256thr/64rows, grid(392,1)  : A f32 subsampled -> q f16 [1024][224][16]
// MODE 2: proj: 256thr/64rows, grid(392,2)  : A f16 [25088][512] -> out f32 [25088][384]
template <int MODE>
__global__ __launch_bounds__(MODE == 0 ? 512 : 256) void gemm_lds(
        const void* __restrict__ Ap, const f16x8* __restrict__ Wg,
        const float* __restrict__ sc, const float* __restrict__ sh,
        void* __restrict__ OutA, f16* __restrict__ OutV) {
    constexpr int K     = (MODE == 2) ? 512 : 256;
    constexpr int KS    = K / 32;
    constexpr int TPB   = (MODE == 0) ? 512 : 256;
    constexpr int NT    = (MODE == 0) ? 640 : (MODE == 1 ? 128 : 384);
    constexpr int CHUNK = (MODE == 2) ? 32 : 64;      // N-cols per LDS stage
    constexpr int NCH   = (MODE == 0) ? 5 : (MODE == 1 ? 2 : 6);
    constexpr int NFR   = CHUNK / 16;                  // B fragments per chunk
    constexpr int UNITS = (K / 8) * CHUNK;             // f16x8 units per chunk = 2048
    constexpr int STAGE_R = UNITS / TPB;

    __shared__ f16x8 Wl[UNITS];                        // 32 KB

    const int t = threadIdx.x;
    const int lane = t & 63, wid = t >> 6;
    const int fr = lane & 15, kg = lane >> 4;
    const int m0 = blockIdx.x * (TPB / 4);             // 16 rows per wave
    const int nb0 = blockIdx.y * (NCH * CHUNK);
    const int mrow = m0 + wid * 16 + fr;

    // ---- A fragments into registers (read once) ----
    size_t arow;
    if constexpr (MODE == 1) {
        int b = mrow / 196, nn = mrow - b * 196;
        arow = (size_t)b * 784 + (nn / 14) * 56 + (nn % 14) * 2;
    } else {
        arow = (size_t)mrow;
    }
    f16x8 af[KS];
#pragma unroll
    for (int ks = 0; ks < KS; ++ks) {
        if constexpr (MODE == 2) {
            af[ks] = *(const f16x8*)((const f16*)Ap + arow * K + ks * 32 + kg * 8);
        } else {
            const float* a = (const float*)Ap + arow * 256 + ks * 32 + kg * 8;
            fvec4 v0 = *(const fvec4*)a;
            fvec4 v1 = *(const fvec4*)(a + 4);
            f16x8 hv;
            hv[0] = (f16)v0[0]; hv[1] = (f16)v0[1]; hv[2] = (f16)v0[2]; hv[3] = (f16)v0[3];
            hv[4] = (f16)v1[0]; hv[5] = (f16)v1[1]; hv[6] = (f16)v1[2]; hv[7] = (f16)v1[3];
            af[ks] = hv;
        }
    }

    const int rg = kg * 4;
    for (int c = 0; c < NCH; ++c) {
        const int n0c = nb0 + c * CHUNK;
        __syncthreads();                               // chunk c-1 consumers done
        // ---- stage W chunk into LDS (coalesced f16x8 copies) ----
#pragma unroll
        for (int rr = 0; rr < STAGE_R; ++rr) {
            const int idx = rr * TPB + t;
            Wl[idx] = Wg[(size_t)(idx / CHUNK) * NT + n0c + (idx % CHUNK)];
        }
        __syncthreads();

        f32x4 acc[NFR];
#pragma unroll
        for (int j = 0; j < NFR; ++j) acc[j] = (f32x4){0.f, 0.f, 0.f, 0.f};

#pragma unroll
        for (int ks = 0; ks < KS; ++ks) {
            f16x8 bfr[NFR];
#pragma unroll
            for (int nf = 0; nf < NFR; ++nf)
                bfr[nf] = Wl[(ks * 4 + kg) * CHUNK + nf * 16 + fr];
#pragma unroll
            for (int nf = 0; nf < NFR; ++nf)
                acc[nf] = mfma16(af[ks], bfr[nf], acc[nf]);
        }

        // ---- epilogue ----
        const int mbase = m0 + wid * 16 + rg;          // 4 consecutive output rows
#pragma unroll
        for (int nf = 0; nf < NFR; ++nf) {
            const int n = n0c + nf * 16 + fr;
            const float scn = sc[n], shn = sh[n];
            if constexpr (MODE == 0) {
                const int b = mbase / 784;
                const int nn = mbase - b * 784;        // %4==0, 4-row group in one b
                const int hd = n / 80;
                const int cc = n - hd * 80;
                const size_t bh = (size_t)(b * 8 + hd);
                if (cc < 16) {
#pragma unroll
                    for (int r = 0; r < 4; ++r) {
                        float y = acc[nf][r] * scn + shn;
                        ((f16*)OutA)[(bh * NKEYP + nn + r) * 16 + cc] = (f16)y;
                    }
                } else {
                    // keyblock-tiled V: [bh][kb][d(64)][key%32]
                    const int kbk = nn >> 5, off = nn & 31;
                    f16x4 pv;
#pragma unroll
                    for (int r = 0; r < 4; ++r) pv[r] = (f16)(acc[nf][r] * scn + shn);
                    *(f16x4*)(OutV + ((bh * 25 + kbk) * 64 + (cc - 16)) * 32 + off) = pv;
                }
            } else if constexpr (MODE == 1) {
                const int b = mbase / 196;
                const int nn = mbase - b * 196;
                const int hd = n >> 4, cc = n & 15;
                const size_t bh = (size_t)(b * 8 + hd);
#pragma unroll
                for (int r = 0; r < 4; ++r) {
                    float y = acc[nf][r] * scn + shn;
                    ((f16*)OutA)[(bh * NQP + nn + r) * 16 + cc] = (f16)y;
                }
            } else {
#pragma unroll
                for (int r = 0; r < 4; ++r) {
                    float y = acc[nf][r] * scn + shn;
                    ((float*)OutA)[(size_t)(mbase + r) * 384 + n] = y;
                }
            }
        }
    }
}

// ---------------- fused attention: block = (b,h), 7 waves = 7 q-tiles ----------------
// V layout: [bh][kb=key/32][d(64)][key%32] — fragment load stays one f16x8.
__global__ __launch_bounds__(448) void attn_fused(const f16* __restrict__ kb,
                                                  const f16* __restrict__ vtb,
                                                  const f16* __restrict__ qw,
                                                  const f16* __restrict__ biasT,
                                                  f16* __restrict__ ao) {
    const int bh = blockIdx.x;
    const int b = bh >> 3, h = bh & 7;
    const int wid = threadIdx.x >> 6;      // q-tile 0..6
    const int lane = threadIdx.x & 63;
    const int l31 = lane & 31;
    const int hh = lane >> 5;
    const int q0 = wid * 32;

    const f16* kp = kb + (size_t)bh * (NKEYP * 16);
    const f16* vp = vtb + (size_t)bh * (25 * 64 * 32) + l31 * 32;
    const f16x8 bq = *(const f16x8*)(qw + ((size_t)bh * NQP + q0 + l31) * 16 + hh * 8);
    const f16* bbq = biasT + ((size_t)h * NQP + (q0 + l31)) * NKEYP;

    float mrun = -1e30f;
    float lsum = 0.f;
    f32x16 o0 = z16(), o1 = z16();

    for (int key0 = 0; key0 < NKEY; key0 += 32) {
        f16x8 ak = *(const f16x8*)(kp + (size_t)(key0 + l31) * 16 + hh * 8);
        f32x16 s = mfma32(ak, bq, z16());
        const bool tail = (key0 + 32) > NKEY;
        f16x4 bw[4];
#pragma unroll
        for (int g = 0; g < 4; ++g)
            bw[g] = *(const f16x4*)(bbq + key0 + g * 8 + hh * 4);
        float p[16];
        float cmax = -3.0e38f;
#pragma unroll
        for (int r = 0; r < 16; ++r) {
            const int cr = (r & 3) + ((r >> 2) << 3) + (hh << 2);
            float sv = s[r] * 0.25f + (float)bw[r >> 2][r & 3];
            if (tail && (key0 + cr) >= NKEY) sv = -1e30f;
            p[r] = sv;
            cmax = fmaxf(cmax, sv);
        }
        cmax = fmaxf(cmax, __shfl_xor(cmax, 32));
        if (__any(cmax > mrun + 8.f)) {          // defer-max
            float mnew = fmaxf(mrun, cmax);
            float f = __expf(mrun - mnew);
            mrun = mnew;
            lsum *= f;
#pragma unroll
            for (int r = 0; r < 16; ++r) {
                const int cr = (r & 3) + ((r >> 2) << 3) + (hh << 2);
                float fr2 = __shfl(f, cr);
                o0[r] *= fr2;
                o1[r] *= fr2;
            }
        }
        float psum = 0.f;
#pragma unroll
        for (int r = 0; r < 16; ++r) {
            p[r] = __expf(p[r] - mrun);
            psum += p[r];
        }
        lsum += psum;
        unsigned g0l = pk2(p[0], p[1]),   g0h = pk2(p[2], p[3]);
        unsigned g1l = pk2(p[4], p[5]),   g1h = pk2(p[6], p[7]);
        unsigned g2l = pk2(p[8], p[9]),   g2h = pk2(p[10], p[11]);
        unsigned g3l = pk2(p[12], p[13]), g3h = pk2(p[14], p[15]);
        __builtin_amdgcn_s_setprio(1);
        const f16* vkb = vp + (key0 >> 5) * (64 * 32);
#pragma unroll
        for (int sH = 0; sH < 2; ++sH) {
            unsigned self_lo = sH ? (hh ? g3l : g2l) : (hh ? g1l : g0l);
            unsigned self_hi = sH ? (hh ? g3h : g2h) : (hh ? g1h : g0h);
            unsigned tx_lo   = sH ? (hh ? g2l : g3l) : (hh ? g0l : g1l);
            unsigned tx_hi   = sH ? (hh ? g2h : g3h) : (hh ? g0h : g1h);
            unsigned rx_lo = __shfl_xor(tx_lo, 32);
            unsigned rx_hi = __shfl_xor(tx_hi, 32);
            uint4v w;
            w[0] = hh ? rx_lo : self_lo;
            w[1] = hh ? rx_hi : self_hi;
            w[2] = hh ? self_lo : rx_lo;
            w[3] = hh ? self_hi : rx_hi;
            f16x8 pa = __builtin_bit_cast(f16x8, w);
            const f16* vrow = vkb + sH * 16 + hh * 8;
            f16x8 bv0 = *(const f16x8*)(vrow);
            f16x8 bv1 = *(const f16x8*)(vrow + 32 * 32);
            o0 = mfma32(pa, bv0, o0);
            o1 = mfma32(pa, bv1, o1);
        }
        __builtin_amdgcn_s_setprio(0);
    }
    lsum += __shfl_xor(lsum, 32);
    const float inv = 1.0f / lsum;
#pragma unroll
    for (int r = 0; r < 16; ++r) {
        const int cr = (r & 3) + ((r >> 2) << 3) + (hh << 2);
        const float iq = __shfl(inv, cr);
        const int qg = q0 + cr;
        if (qg < NQ) {
            float v0 = o0[r] * iq, v1 = o1[r] * iq;
            float h0 = v0 * fminf(fmaxf(v0 + 3.f, 0.f), 6.f) * (1.f / 6.f);
            float h1 = v1 * fminf(fmaxf(v1 + 3.f, 0.f), 6.f) * (1.f / 6.f);
            f16* dst = ao + ((size_t)b * NQ + qg) * 512 + h * 64 + l31;
            dst[0] = (f16)h0;
            dst[32] = (f16)h1;
        }
    }
}

// ---------------- launch ----------------
extern "C" void kernel_launch(void* const* d_in, const int* in_sizes, int n_in,
                              void* d_out, int out_size, void* d_ws, size_t ws_size,
                              hipStream_t stream) {
    (void)n_in; (void)out_size; (void)ws_size;
    const float* hidden = (const float*)d_in[0];
    const float* w_kv   = (const float*)d_in[1];
    const float* w_q    = (const float*)d_in[6];
    const float* w_p    = (const float*)d_in[11];
    const float* biases = (const float*)d_in[16];
    const int*   idxs   = (const int*)d_in[17];
    const int n_off = in_sizes[16] / 8;

    char* ws = (char*)d_ws;
    const size_t OFF_K  = 0;                       // 26,214,400
    const size_t OFF_V  = 26214400;                // 104,857,600
    const size_t OFF_Q  = 131072000;               //   7,340,032
    const size_t OFF_AO = 138412032;               //  25,690,112
    const size_t OFF_BT = 164102144;               //   2,867,200
    const size_t OFF_W  = 166969344;               //     786,432
    const size_t OFF_SC = 167755776;               //       9,216
    f16*   kbuf  = (f16*)(ws + OFF_K);
    f16*   vbuf  = (f16*)(ws + OFF_V);
    f16*   qbuf  = (f16*)(ws + OFF_Q);
    f16*   aobuf = (f16*)(ws + OFF_AO);
    f16*   btbuf = (f16*)(ws + OFF_BT);
    f16*   wf16  = (f16*)(ws + OFF_W);
    float* scbuf = (float*)(ws + OFF_SC);

    prep_scales_all<<<5, 256, 0, stream>>>(
        (const float*)d_in[2], (const float*)d_in[3], (const float*)d_in[4], (const float*)d_in[5],
        (const float*)d_in[7], (const float*)d_in[8], (const float*)d_in[9], (const float*)d_in[10],
        (const float*)d_in[12], (const float*)d_in[13], (const float*)d_in[14], (const float*)d_in[15],
        scbuf);
    conv_w<<<192, 256, 0, stream>>>(w_kv, w_q, w_p, wf16);
    prep_bias<<<5600, 256, 0, stream>>>(biases, idxs, btbuf, n_off);
    hipMemsetAsync(qbuf, 0, (size_t)1024 * NQP * 16 * 2, stream);  // zero q pad rows
    gemm_lds<0><<<dim3(784, 2), 512, 0, stream>>>(hidden, (const f16x8*)wf16, scbuf, scbuf + 640, kbuf, vbuf);
    gemm_lds<1><<<dim3(392, 1), 256, 0, stream>>>(hidden, (const f16x8*)(wf16 + 163840), scbuf + 1280, scbuf + 1408, qbuf, nullptr);
    attn_fused<<<1024, 448, 0, stream>>>(kbuf, vbuf, qbuf, btbuf, aobuf);
    gemm_lds<2><<<dim3(392, 2), 256, 0, stream>>>(aobuf, (const f16x8*)(wf16 + 196608), scbuf + 1536, scbuf + 1920, d_out, nullptr);
}

// Round 9
// 226.589 us; speedup vs baseline: 1.6929x; 1.0742x over previous
//
#include <hip/hip_runtime.h>

typedef _Float16 f16;
typedef __attribute__((ext_vector_type(2))) _Float16 f16x2;
typedef __attribute__((ext_vector_type(4))) _Float16 f16x4;
typedef __attribute__((ext_vector_type(8))) _Float16 f16x8;
typedef __attribute__((ext_vector_type(4))) float fvec4;
typedef __attribute__((ext_vector_type(4))) float f32x4;
typedef __attribute__((ext_vector_type(16))) float f32x16;
typedef __attribute__((ext_vector_type(4))) unsigned int uint4v;

#define NKEY 784
#define NKEYP 800
#define NQ 196
#define NQP 224

static __device__ __forceinline__ f32x4 mfma16(f16x8 a, f16x8 b, f32x4 c) {
    return __builtin_amdgcn_mfma_f32_16x16x32_f16(a, b, c, 0, 0, 0);
}
static __device__ __forceinline__ f32x16 mfma32(f16x8 a, f16x8 b, f32x16 c) {
    return __builtin_amdgcn_mfma_f32_32x32x16_f16(a, b, c, 0, 0, 0);
}
static __device__ __forceinline__ unsigned pk2(float a, float b) {
    f16x2 t; t[0] = (_Float16)a; t[1] = (_Float16)b;
    return __builtin_bit_cast(unsigned, t);
}
static __device__ __forceinline__ f32x16 z16() {
    f32x16 v;
#pragma unroll
    for (int i = 0; i < 16; ++i) v[i] = 0.f;
    return v;
}

// ---------------- prep: fold BN into scale/shift (all three BNs) ----------------
__global__ void prep_scales_all(const float* __restrict__ kg, const float* __restrict__ kb,
                                const float* __restrict__ km, const float* __restrict__ kvv,
                                const float* __restrict__ qg, const float* __restrict__ qb,
                                const float* __restrict__ qm, const float* __restrict__ qv,
                                const float* __restrict__ pg, const float* __restrict__ pb,
                                const float* __restrict__ pm, const float* __restrict__ pv,
                                float* __restrict__ sb) {
    int i = blockIdx.x * 256 + threadIdx.x;
    if (i < 640) {
        float s = kg[i] * rsqrtf(kvv[i] + 1e-5f);
        sb[i] = s; sb[640 + i] = kb[i] - km[i] * s;
    } else if (i < 768) {
        int j = i - 640;
        float s = qg[j] * rsqrtf(qv[j] + 1e-5f);
        sb[1280 + j] = s; sb[1408 + j] = qb[j] - qm[j] * s;
    } else if (i < 1152) {
        int j = i - 768;
        float s = pg[j] * rsqrtf(pv[j] + 1e-5f);
        sb[1536 + j] = s; sb[1920 + j] = pb[j] - pm[j] * s;
    }
}

// ---------------- prep: convert weights to f16, k-major fragment layout ----------------
// Wt element (n, k) at [(k/8)*NT + n]*8 + (k%8)  (per weight matrix)
__global__ void conv_w(const float* __restrict__ wkv, const float* __restrict__ wq,
                       const float* __restrict__ wp, f16* __restrict__ out) {
    int i = blockIdx.x * 256 + threadIdx.x;   // 49152 threads = 20480 + 4096 + 24576
    const float* src;
    f16* dst;
    int kc, n, K;
    if (i < 20480)      { int j = i;         kc = j / 640, n = j - kc * 640; src = wkv; dst = out + (size_t)j * 8;            K = 256; }
    else if (i < 24576) { int j = i - 20480; kc = j / 128, n = j - kc * 128; src = wq;  dst = out + 163840 + (size_t)j * 8;   K = 256; }
    else                { int j = i - 24576; kc = j / 384, n = j - kc * 384; src = wp;  dst = out + 196608 + (size_t)j * 8;   K = 512; }
    const float* s = src + (size_t)n * K + kc * 8;
    fvec4 v0 = *(const fvec4*)s;
    fvec4 v1 = *(const fvec4*)(s + 4);
    f16x8 h;
    h[0] = (f16)v0[0]; h[1] = (f16)v0[1]; h[2] = (f16)v0[2]; h[3] = (f16)v0[3];
    h[4] = (f16)v1[0]; h[5] = (f16)v1[1]; h[6] = (f16)v1[2]; h[7] = (f16)v1[3];
    *(f16x8*)dst = h;
}

// ---------------- prep: gather bias f16 [h][q(224)][key(800)] ----------------
__global__ void prep_bias(const float* __restrict__ biases, const int* __restrict__ idxs,
                          f16* __restrict__ biasT, int n_off) {
    int tid = blockIdx.x * 256 + threadIdx.x;   // 8*224*800
    int h = tid / (NQP * NKEYP);
    int rem = tid - h * (NQP * NKEYP);
    int q = rem / NKEYP;
    int key = rem - q * NKEYP;
    float v = 0.f;
    if (q < NQ && key < NKEY) v = biases[h * n_off + idxs[q * NKEY + key]];
    biasT[tid] = (f16)v;
}

// ---------------- GEMM: A in registers, W chunks double-buffered in LDS ----------------
// T3-min pattern: per chunk {issue next-chunk global loads -> compute current from LDS
// -> ds_write next -> ONE barrier}. L2 stage latency hides under MFMA compute.
// MODE 0: kv  : 256thr/64rows, CHUNK=32, grid(1568,2): A f32 -> K f16 [1024][800][16]
//                                                        + V f16 [1024][25][64][32]
// MODE 1: q   : 256thr/64rows, CHUNK=32, grid(392,1)
// MODE 2: proj: 256thr/64rows, CHUNK=16 (K=512), grid(392,2)
template <int MODE>
__global__ __launch_bounds__(256) void gemm_db(
        const void* __restrict__ Ap, const f16x8* __restrict__ Wg,
        const float* __restrict__ sc, const float* __restrict__ sh,
        void* __restrict__ OutA, f16* __restrict__ OutV) {
    constexpr int K     = (MODE == 2) ? 512 : 256;
    constexpr int KS    = K / 32;                 // 8 or 16
    constexpr int CHUNK = (MODE == 2) ? 16 : 32;  // N-cols per LDS stage
    constexpr int NFR   = CHUNK / 16;             // 2 or 1
    constexpr int NT    = (MODE == 0) ? 640 : (MODE == 1 ? 128 : 384);
    constexpr int NCH   = (MODE == 0) ? 10 : (MODE == 1 ? 4 : 12);
    constexpr int UNITS = (K / 8) * CHUNK;        // 1024 f16x8 = 16 KB
    constexpr int SR    = UNITS / 256;            // 4 stage units per thread

    __shared__ f16x8 Wl[2][UNITS];                // 32 KB double buffer

    const int t = threadIdx.x;
    const int lane = t & 63, wid = t >> 6;
    const int fr = lane & 15, kg = lane >> 4;
    const int m0 = blockIdx.x * 64;
    const int nb0 = blockIdx.y * (NCH * CHUNK);
    const int mrow = m0 + wid * 16 + fr;

    // ---- A fragments into registers (read once per block) ----
    size_t arow;
    if constexpr (MODE == 1) {
        int b = mrow / 196, nn = mrow - b * 196;
        arow = (size_t)b * 784 + (nn / 14) * 56 + (nn % 14) * 2;
    } else {
        arow = (size_t)mrow;
    }
    f16x8 af[KS];
#pragma unroll
    for (int ks = 0; ks < KS; ++ks) {
        if constexpr (MODE == 2) {
            af[ks] = *(const f16x8*)((const f16*)Ap + arow * K + ks * 32 + kg * 8);
        } else {
            const float* a = (const float*)Ap + arow * 256 + ks * 32 + kg * 8;
            fvec4 v0 = *(const fvec4*)a;
            fvec4 v1 = *(const fvec4*)(a + 4);
            f16x8 hv;
            hv[0] = (f16)v0[0]; hv[1] = (f16)v0[1]; hv[2] = (f16)v0[2]; hv[3] = (f16)v0[3];
            hv[4] = (f16)v1[0]; hv[5] = (f16)v1[1]; hv[6] = (f16)v1[2]; hv[7] = (f16)v1[3];
            af[ks] = hv;
        }
    }

    // per-thread stage coordinates (idx = rr*256 + t)
    // global unit: (idx/CHUNK)*NT + n0c + idx%CHUNK ; LDS unit: idx
    // ---- prologue: stage chunk 0 ----
#pragma unroll
    for (int rr = 0; rr < SR; ++rr) {
        const int idx = rr * 256 + t;
        Wl[0][idx] = Wg[(size_t)(idx / CHUNK) * NT + nb0 + (idx % CHUNK)];
    }
    __syncthreads();

    const int rg = kg * 4;
    int cur = 0;
    for (int c = 0; c < NCH; ++c) {
        const int n0c = nb0 + c * CHUNK;

        // ---- issue next-chunk loads early (latency hides under compute) ----
        f16x8 nx0, nx1, nx2, nx3;
        if (c + 1 < NCH) {
            const int n0n = n0c + CHUNK;
            nx0 = Wg[(size_t)((0 * 256 + t) / CHUNK) * NT + n0n + ((0 * 256 + t) % CHUNK)];
            nx1 = Wg[(size_t)((1 * 256 + t) / CHUNK) * NT + n0n + ((1 * 256 + t) % CHUNK)];
            nx2 = Wg[(size_t)((2 * 256 + t) / CHUNK) * NT + n0n + ((2 * 256 + t) % CHUNK)];
            nx3 = Wg[(size_t)((3 * 256 + t) / CHUNK) * NT + n0n + ((3 * 256 + t) % CHUNK)];
        }

        // ---- compute current chunk from LDS ----
        f32x4 acc[NFR];
#pragma unroll
        for (int j = 0; j < NFR; ++j) acc[j] = (f32x4){0.f, 0.f, 0.f, 0.f};
#pragma unroll
        for (int ks = 0; ks < KS; ++ks) {
            f16x8 bfr[NFR];
#pragma unroll
            for (int nf = 0; nf < NFR; ++nf)
                bfr[nf] = Wl[cur][(ks * 4 + kg) * CHUNK + nf * 16 + fr];
#pragma unroll
            for (int nf = 0; nf < NFR; ++nf)
                acc[nf] = mfma16(af[ks], bfr[nf], acc[nf]);
        }

        // ---- epilogue ----
        const int mbase = m0 + wid * 16 + rg;     // 4 consecutive output rows
#pragma unroll
        for (int nf = 0; nf < NFR; ++nf) {
            const int n = n0c + nf * 16 + fr;
            const float scn = sc[n], shn = sh[n];
            if constexpr (MODE == 0) {
                const int b = mbase / 784;
                const int nn = mbase - b * 784;   // %4==0, 4-row group in one b
                const int hd = n / 80;
                const int cc = n - hd * 80;
                const size_t bh = (size_t)(b * 8 + hd);
                if (cc < 16) {
#pragma unroll
                    for (int r = 0; r < 4; ++r) {
                        float y = acc[nf][r] * scn + shn;
                        ((f16*)OutA)[(bh * NKEYP + nn + r) * 16 + cc] = (f16)y;
                    }
                } else {
                    const int kbk = nn >> 5, off = nn & 31;
                    f16x4 pv;
#pragma unroll
                    for (int r = 0; r < 4; ++r) pv[r] = (f16)(acc[nf][r] * scn + shn);
                    *(f16x4*)(OutV + ((bh * 25 + kbk) * 64 + (cc - 16)) * 32 + off) = pv;
                }
            } else if constexpr (MODE == 1) {
                const int b = mbase / 196;
                const int nn = mbase - b * 196;
                const int hd = n >> 4, cc = n & 15;
                const size_t bh = (size_t)(b * 8 + hd);
#pragma unroll
                for (int r = 0; r < 4; ++r) {
                    float y = acc[nf][r] * scn + shn;
                    ((f16*)OutA)[(bh * NQP + nn + r) * 16 + cc] = (f16)y;
                }
            } else {
#pragma unroll
                for (int r = 0; r < 4; ++r) {
                    float y = acc[nf][r] * scn + shn;
                    ((float*)OutA)[(size_t)(mbase + r) * 384 + n] = y;
                }
            }
        }

        // ---- write next chunk into other buffer, single barrier ----
        if (c + 1 < NCH) {
            Wl[cur ^ 1][0 * 256 + t] = nx0;
            Wl[cur ^ 1][1 * 256 + t] = nx1;
            Wl[cur ^ 1][2 * 256 + t] = nx2;
            Wl[cur ^ 1][3 * 256 + t] = nx3;
            __syncthreads();
            cur ^= 1;
        }
    }
}

// ---------------- fused attention: block = (b,h), 7 waves = 7 q-tiles ----------------
// V layout: [bh][kb=key/32][d(64)][key%32] — fragment load stays one f16x8.
__global__ __launch_bounds__(448) void attn_fused(const f16* __restrict__ kb,
                                                  const f16* __restrict__ vtb,
                                                  const f16* __restrict__ qw,
                                                  const f16* __restrict__ biasT,
                                                  f16* __restrict__ ao) {
    const int bh = blockIdx.x;
    const int b = bh >> 3, h = bh & 7;
    const int wid = threadIdx.x >> 6;      // q-tile 0..6
    const int lane = threadIdx.x & 63;
    const int l31 = lane & 31;
    const int hh = lane >> 5;
    const int q0 = wid * 32;

    const f16* kp = kb + (size_t)bh * (NKEYP * 16);
    const f16* vp = vtb + (size_t)bh * (25 * 64 * 32) + l31 * 32;
    const f16x8 bq = *(const f16x8*)(qw + ((size_t)bh * NQP + q0 + l31) * 16 + hh * 8);
    const f16* bbq = biasT + ((size_t)h * NQP + (q0 + l31)) * NKEYP;

    float mrun = -1e30f;
    float lsum = 0.f;
    f32x16 o0 = z16(), o1 = z16();

    for (int key0 = 0; key0 < NKEY; key0 += 32) {
        f16x8 ak = *(const f16x8*)(kp + (size_t)(key0 + l31) * 16 + hh * 8);
        f32x16 s = mfma32(ak, bq, z16());
        const bool tail = (key0 + 32) > NKEY;
        f16x4 bw[4];
#pragma unroll
        for (int g = 0; g < 4; ++g)
            bw[g] = *(const f16x4*)(bbq + key0 + g * 8 + hh * 4);
        float p[16];
        float cmax = -3.0e38f;
#pragma unroll
        for (int r = 0; r < 16; ++r) {
            const int cr = (r & 3) + ((r >> 2) << 3) + (hh << 2);
            float sv = s[r] * 0.25f + (float)bw[r >> 2][r & 3];
            if (tail && (key0 + cr) >= NKEY) sv = -1e30f;
            p[r] = sv;
            cmax = fmaxf(cmax, sv);
        }
        cmax = fmaxf(cmax, __shfl_xor(cmax, 32));
        if (__any(cmax > mrun + 8.f)) {          // defer-max
            float mnew = fmaxf(mrun, cmax);
            float f = __expf(mrun - mnew);
            mrun = mnew;
            lsum *= f;
#pragma unroll
            for (int r = 0; r < 16; ++r) {
                const int cr = (r & 3) + ((r >> 2) << 3) + (hh << 2);
                float fr2 = __shfl(f, cr);
                o0[r] *= fr2;
                o1[r] *= fr2;
            }
        }
        float psum = 0.f;
#pragma unroll
        for (int r = 0; r < 16; ++r) {
            p[r] = __expf(p[r] - mrun);
            psum += p[r];
        }
        lsum += psum;
        unsigned g0l = pk2(p[0], p[1]),   g0h = pk2(p[2], p[3]);
        unsigned g1l = pk2(p[4], p[5]),   g1h = pk2(p[6], p[7]);
        unsigned g2l = pk2(p[8], p[9]),   g2h = pk2(p[10], p[11]);
        unsigned g3l = pk2(p[12], p[13]), g3h = pk2(p[14], p[15]);
        __builtin_amdgcn_s_setprio(1);
        const f16* vkb = vp + (key0 >> 5) * (64 * 32);
#pragma unroll
        for (int sH = 0; sH < 2; ++sH) {
            unsigned self_lo = sH ? (hh ? g3l : g2l) : (hh ? g1l : g0l);
            unsigned self_hi = sH ? (hh ? g3h : g2h) : (hh ? g1h : g0h);
            unsigned tx_lo   = sH ? (hh ? g2l : g3l) : (hh ? g0l : g1l);
            unsigned tx_hi   = sH ? (hh ? g2h : g3h) : (hh ? g0h : g1h);
            unsigned rx_lo = __shfl_xor(tx_lo, 32);
            unsigned rx_hi = __shfl_xor(tx_hi, 32);
            uint4v w;
            w[0] = hh ? rx_lo : self_lo;
            w[1] = hh ? rx_hi : self_hi;
            w[2] = hh ? self_lo : rx_lo;
            w[3] = hh ? self_hi : rx_hi;
            f16x8 pa = __builtin_bit_cast(f16x8, w);
            const f16* vrow = vkb + sH * 16 + hh * 8;
            f16x8 bv0 = *(const f16x8*)(vrow);
            f16x8 bv1 = *(const f16x8*)(vrow + 32 * 32);
            o0 = mfma32(pa, bv0, o0);
            o1 = mfma32(pa, bv1, o1);
        }
        __builtin_amdgcn_s_setprio(0);
    }
    lsum += __shfl_xor(lsum, 32);
    const float inv = 1.0f / lsum;
#pragma unroll
    for (int r = 0; r < 16; ++r) {
        const int cr = (r & 3) + ((r >> 2) << 3) + (hh << 2);
        const float iq = __shfl(inv, cr);
        const int qg = q0 + cr;
        if (qg < NQ) {
            float v0 = o0[r] * iq, v1 = o1[r] * iq;
            float h0 = v0 * fminf(fmaxf(v0 + 3.f, 0.f), 6.f) * (1.f / 6.f);
            float h1 = v1 * fminf(fmaxf(v1 + 3.f, 0.f), 6.f) * (1.f / 6.f);
            f16* dst = ao + ((size_t)b * NQ + qg) * 512 + h * 64 + l31;
            dst[0] = (f16)h0;
            dst[32] = (f16)h1;
        }
    }
}

// ---------------- launch ----------------
extern "C" void kernel_launch(void* const* d_in, const int* in_sizes, int n_in,
                              void* d_out, int out_size, void* d_ws, size_t ws_size,
                              hipStream_t stream) {
    (void)n_in; (void)out_size; (void)ws_size;
    const float* hidden = (const float*)d_in[0];
    const float* w_kv   = (const float*)d_in[1];
    const float* w_q    = (const float*)d_in[6];
    const float* w_p    = (const float*)d_in[11];
    const float* biases = (const float*)d_in[16];
    const int*   idxs   = (const int*)d_in[17];
    const int n_off = in_sizes[16] / 8;

    char* ws = (char*)d_ws;
    const size_t OFF_K  = 0;                       // 26,214,400
    const size_t OFF_V  = 26214400;                // 104,857,600
    const size_t OFF_Q  = 131072000;               //   7,340,032
    const size_t OFF_AO = 138412032;               //  25,690,112
    const size_t OFF_BT = 164102144;               //   2,867,200
    const size_t OFF_W  = 166969344;               //     786,432
    const size_t OFF_SC = 167755776;               //       9,216
    f16*   kbuf  = (f16*)(ws + OFF_K);
    f16*   vbuf  = (f16*)(ws + OFF_V);
    f16*   qbuf  = (f16*)(ws + OFF_Q);
    f16*   aobuf = (f16*)(ws + OFF_AO);
    f16*   btbuf = (f16*)(ws + OFF_BT);
    f16*   wf16  = (f16*)(ws + OFF_W);
    float* scbuf = (float*)(ws + OFF_SC);

    prep_scales_all<<<5, 256, 0, stream>>>(
        (const float*)d_in[2], (const float*)d_in[3], (const float*)d_in[4], (const float*)d_in[5],
        (const float*)d_in[7], (const float*)d_in[8], (const float*)d_in[9], (const float*)d_in[10],
        (const float*)d_in[12], (const float*)d_in[13], (const float*)d_in[14], (const float*)d_in[15],
        scbuf);
    conv_w<<<192, 256, 0, stream>>>(w_kv, w_q, w_p, wf16);
    prep_bias<<<5600, 256, 0, stream>>>(biases, idxs, btbuf, n_off);
    hipMemsetAsync(qbuf, 0, (size_t)1024 * NQP * 16 * 2, stream);  // zero q pad rows
    gemm_db<0><<<dim3(1568, 2), 256, 0, stream>>>(hidden, (const f16x8*)wf16, scbuf, scbuf + 640, kbuf, vbuf);
    gemm_db<1><<<dim3(392, 1), 256, 0, stream>>>(hidden, (const f16x8*)(wf16 + 163840), scbuf + 1280, scbuf + 1408, qbuf, nullptr);
    attn_fused<<<1024, 448, 0, stream>>>(kbuf, vbuf, qbuf, btbuf, aobuf);
    gemm_db<2><<<dim3(392, 2), 256, 0, stream>>>(aobuf, (const f16x8*)(wf16 + 196608), scbuf + 1536, scbuf + 1920, d_out, nullptr);
}

// Round 10
// 222.172 us; speedup vs baseline: 1.7265x; 1.0199x over previous
//
#include <hip/hip_runtime.h>

typedef _Float16 f16;
typedef __attribute__((ext_vector_type(2))) _Float16 f16x2;
typedef __attribute__((ext_vector_type(4))) _Float16 f16x4;
typedef __attribute__((ext_vector_type(8))) _Float16 f16x8;
typedef __attribute__((ext_vector_type(4))) float fvec4;
typedef __attribute__((ext_vector_type(4))) float f32x4;
typedef __attribute__((ext_vector_type(16))) float f32x16;
typedef __attribute__((ext_vector_type(4))) unsigned int uint4v;

#define NKEY 784
#define NKEYP 800
#define NQ 196
#define NQP 224
#define LOG2E 1.442695041f
#define SC2   0.360673760f   /* 0.25 * log2(e) */
#define THR2  11.5415603f    /* 8 * log2(e) */

static __device__ __forceinline__ f32x4 mfma16(f16x8 a, f16x8 b, f32x4 c) {
    return __builtin_amdgcn_mfma_f32_16x16x32_f16(a, b, c, 0, 0, 0);
}
static __device__ __forceinline__ f32x16 mfma32(f16x8 a, f16x8 b, f32x16 c) {
    return __builtin_amdgcn_mfma_f32_32x32x16_f16(a, b, c, 0, 0, 0);
}
static __device__ __forceinline__ unsigned pk2(float a, float b) {
    f16x2 t; t[0] = (_Float16)a; t[1] = (_Float16)b;
    return __builtin_bit_cast(unsigned, t);
}
static __device__ __forceinline__ f32x16 z16() {
    f32x16 v;
#pragma unroll
    for (int i = 0; i < 16; ++i) v[i] = 0.f;
    return v;
}

// ---------------- prep: fold BN into scale/shift (all three BNs) ----------------
__global__ void prep_scales_all(const float* __restrict__ kg, const float* __restrict__ kb,
                                const float* __restrict__ km, const float* __restrict__ kvv,
                                const float* __restrict__ qg, const float* __restrict__ qb,
                                const float* __restrict__ qm, const float* __restrict__ qv,
                                const float* __restrict__ pg, const float* __restrict__ pb,
                                const float* __restrict__ pm, const float* __restrict__ pv,
                                float* __restrict__ sb) {
    int i = blockIdx.x * 256 + threadIdx.x;
    if (i < 640) {
        float s = kg[i] * rsqrtf(kvv[i] + 1e-5f);
        sb[i] = s; sb[640 + i] = kb[i] - km[i] * s;
    } else if (i < 768) {
        int j = i - 640;
        float s = qg[j] * rsqrtf(qv[j] + 1e-5f);
        sb[1280 + j] = s; sb[1408 + j] = qb[j] - qm[j] * s;
    } else if (i < 1152) {
        int j = i - 768;
        float s = pg[j] * rsqrtf(pv[j] + 1e-5f);
        sb[1536 + j] = s; sb[1920 + j] = pb[j] - pm[j] * s;
    }
}

// ---------------- prep: convert weights to f16, k-major fragment layout ----------------
__global__ void conv_w(const float* __restrict__ wkv, const float* __restrict__ wq,
                       const float* __restrict__ wp, f16* __restrict__ out) {
    int i = blockIdx.x * 256 + threadIdx.x;   // 49152 threads
    const float* src;
    f16* dst;
    int kc, n, K;
    if (i < 20480)      { int j = i;         kc = j / 640, n = j - kc * 640; src = wkv; dst = out + (size_t)j * 8;            K = 256; }
    else if (i < 24576) { int j = i - 20480; kc = j / 128, n = j - kc * 128; src = wq;  dst = out + 163840 + (size_t)j * 8;   K = 256; }
    else                { int j = i - 24576; kc = j / 384, n = j - kc * 384; src = wp;  dst = out + 196608 + (size_t)j * 8;   K = 512; }
    const float* s = src + (size_t)n * K + kc * 8;
    fvec4 v0 = *(const fvec4*)s;
    fvec4 v1 = *(const fvec4*)(s + 4);
    f16x8 h;
    h[0] = (f16)v0[0]; h[1] = (f16)v0[1]; h[2] = (f16)v0[2]; h[3] = (f16)v0[3];
    h[4] = (f16)v1[0]; h[5] = (f16)v1[1]; h[6] = (f16)v1[2]; h[7] = (f16)v1[3];
    *(f16x8*)dst = h;
}

// ---------------- prep: gather bias in (lane,r) consumption order, log2 domain ----------------
// biasS[h][qt(7)][kb(25)][lane(64)][r(16)] = bias[h][q=qt*32+(lane&31)][key=kb*32+cr] * log2e
// cr = (r&3) + 8*(r>>2) + 4*(lane>>5)
__global__ void prep_bias(const float* __restrict__ biases, const int* __restrict__ idxs,
                          f16* __restrict__ biasS, int n_off) {
    int tid = blockIdx.x * 256 + threadIdx.x;   // 1,433,600 threads
    const int r = tid & 15;
    const int lane = (tid >> 4) & 63;
    const int g = tid >> 10;                    // [h][qt][kb], 1400 groups
    const int kbk = g % 25;
    const int tmp = g / 25;
    const int qt = tmp % 7;
    const int h = tmp / 7;
    const int q = qt * 32 + (lane & 31);
    const int key = kbk * 32 + (r & 3) + 8 * (r >> 2) + 4 * (lane >> 5);
    float v = 0.f;
    if (q < NQ && key < NKEY) v = biases[h * n_off + idxs[q * NKEY + key]] * LOG2E;
    biasS[tid] = (f16)v;
}

// ---------------- GEMM: A in registers, W chunks double-buffered in LDS ----------------
// MODE 0: kv  : 256thr/64rows, CHUNK=32, grid(1568,2): A f32 -> K f16 [1024][800][16]
//               + V f16 [bh][kb(25)][sH(2)][d(64)][key16(16)]
// MODE 1: q   : 256thr/64rows, CHUNK=32, grid(392,1)
// MODE 2: proj: 256thr/64rows, CHUNK=16 (K=512), grid(392,2)
template <int MODE>
__global__ __launch_bounds__(256) void gemm_db(
        const void* __restrict__ Ap, const f16x8* __restrict__ Wg,
        const float* __restrict__ sc, const float* __restrict__ sh,
        void* __restrict__ OutA, f16* __restrict__ OutV) {
    constexpr int K     = (MODE == 2) ? 512 : 256;
    constexpr int KS    = K / 32;
    constexpr int CHUNK = (MODE == 2) ? 16 : 32;
    constexpr int NFR   = CHUNK / 16;
    constexpr int NT    = (MODE == 0) ? 640 : (MODE == 1 ? 128 : 384);
    constexpr int NCH   = (MODE == 0) ? 10 : (MODE == 1 ? 4 : 12);
    constexpr int UNITS = (K / 8) * CHUNK;
    constexpr int SR    = UNITS / 256;

    __shared__ f16x8 Wl[2][UNITS];

    const int t = threadIdx.x;
    const int lane = t & 63, wid = t >> 6;
    const int fr = lane & 15, kg = lane >> 4;
    const int m0 = blockIdx.x * 64;
    const int nb0 = blockIdx.y * (NCH * CHUNK);
    const int mrow = m0 + wid * 16 + fr;

    size_t arow;
    if constexpr (MODE == 1) {
        int b = mrow / 196, nn = mrow - b * 196;
        arow = (size_t)b * 784 + (nn / 14) * 56 + (nn % 14) * 2;
    } else {
        arow = (size_t)mrow;
    }
    f16x8 af[KS];
#pragma unroll
    for (int ks = 0; ks < KS; ++ks) {
        if constexpr (MODE == 2) {
            af[ks] = *(const f16x8*)((const f16*)Ap + arow * K + ks * 32 + kg * 8);
        } else {
            const float* a = (const float*)Ap + arow * 256 + ks * 32 + kg * 8;
            fvec4 v0 = *(const fvec4*)a;
            fvec4 v1 = *(const fvec4*)(a + 4);
            f16x8 hv;
            hv[0] = (f16)v0[0]; hv[1] = (f16)v0[1]; hv[2] = (f16)v0[2]; hv[3] = (f16)v0[3];
            hv[4] = (f16)v1[0]; hv[5] = (f16)v1[1]; hv[6] = (f16)v1[2]; hv[7] = (f16)v1[3];
            af[ks] = hv;
        }
    }

    // ---- prologue: stage chunk 0 ----
#pragma unroll
    for (int rr = 0; rr < SR; ++rr) {
        const int idx = rr * 256 + t;
        Wl[0][idx] = Wg[(size_t)(idx / CHUNK) * NT + nb0 + (idx % CHUNK)];
    }
    __syncthreads();

    const int rg = kg * 4;
    int cur = 0;
    for (int c = 0; c < NCH; ++c) {
        const int n0c = nb0 + c * CHUNK;

        f16x8 nx0, nx1, nx2, nx3;
        if (c + 1 < NCH) {
            const int n0n = n0c + CHUNK;
            nx0 = Wg[(size_t)((0 * 256 + t) / CHUNK) * NT + n0n + ((0 * 256 + t) % CHUNK)];
            nx1 = Wg[(size_t)((1 * 256 + t) / CHUNK) * NT + n0n + ((1 * 256 + t) % CHUNK)];
            nx2 = Wg[(size_t)((2 * 256 + t) / CHUNK) * NT + n0n + ((2 * 256 + t) % CHUNK)];
            nx3 = Wg[(size_t)((3 * 256 + t) / CHUNK) * NT + n0n + ((3 * 256 + t) % CHUNK)];
        }

        f32x4 acc[NFR];
#pragma unroll
        for (int j = 0; j < NFR; ++j) acc[j] = (f32x4){0.f, 0.f, 0.f, 0.f};
#pragma unroll
        for (int ks = 0; ks < KS; ++ks) {
            f16x8 bfr[NFR];
#pragma unroll
            for (int nf = 0; nf < NFR; ++nf)
                bfr[nf] = Wl[cur][(ks * 4 + kg) * CHUNK + nf * 16 + fr];
#pragma unroll
            for (int nf = 0; nf < NFR; ++nf)
                acc[nf] = mfma16(af[ks], bfr[nf], acc[nf]);
        }

        const int mbase = m0 + wid * 16 + rg;
#pragma unroll
        for (int nf = 0; nf < NFR; ++nf) {
            const int n = n0c + nf * 16 + fr;
            const float scn = sc[n], shn = sh[n];
            if constexpr (MODE == 0) {
                const int b = mbase / 784;
                const int nn = mbase - b * 784;
                const int hd = n / 80;
                const int cc = n - hd * 80;
                const size_t bh = (size_t)(b * 8 + hd);
                if (cc < 16) {
#pragma unroll
                    for (int r = 0; r < 4; ++r) {
                        float y = acc[nf][r] * scn + shn;
                        ((f16*)OutA)[(bh * NKEYP + nn + r) * 16 + cc] = (f16)y;
                    }
                } else {
                    // V layout: [bh][kb][sH][d(64)][key16]
                    const int kbk = nn >> 5, sH = (nn >> 4) & 1, kk = nn & 15;
                    f16x4 pv;
#pragma unroll
                    for (int r = 0; r < 4; ++r) pv[r] = (f16)(acc[nf][r] * scn + shn);
                    *(f16x4*)(OutV + ((bh * 25 + kbk) * 2 + sH) * 1024 + (cc - 16) * 16 + kk) = pv;
                }
            } else if constexpr (MODE == 1) {
                const int b = mbase / 196;
                const int nn = mbase - b * 196;
                const int hd = n >> 4, cc = n & 15;
                const size_t bh = (size_t)(b * 8 + hd);
#pragma unroll
                for (int r = 0; r < 4; ++r) {
                    float y = acc[nf][r] * scn + shn;
                    ((f16*)OutA)[(bh * NQP + nn + r) * 16 + cc] = (f16)y;
                }
            } else {
#pragma unroll
                for (int r = 0; r < 4; ++r) {
                    float y = acc[nf][r] * scn + shn;
                    ((float*)OutA)[(size_t)(mbase + r) * 384 + n] = y;
                }
            }
        }

        if (c + 1 < NCH) {
            Wl[cur ^ 1][0 * 256 + t] = nx0;
            Wl[cur ^ 1][1 * 256 + t] = nx1;
            Wl[cur ^ 1][2 * 256 + t] = nx2;
            Wl[cur ^ 1][3 * 256 + t] = nx3;
            __syncthreads();
            cur ^= 1;
        }
    }
}

// ---------------- fused attention: block = (b,h), 7 waves = 7 q-tiles ----------------
// All loads lane-contiguous: K [key][16], V [kb][sH][d][key16], bias [qt][kb][lane][r].
// Softmax in log2 domain (scores pre-scaled by log2e).
__global__ __launch_bounds__(448) void attn_fused(const f16* __restrict__ kb,
                                                  const f16* __restrict__ vtb,
                                                  const f16* __restrict__ qw,
                                                  const f16* __restrict__ biasS,
                                                  f16* __restrict__ ao) {
    const int bh = blockIdx.x;
    const int b = bh >> 3, h = bh & 7;
    const int wid = threadIdx.x >> 6;      // q-tile 0..6
    const int lane = threadIdx.x & 63;
    const int l31 = lane & 31;
    const int hh = lane >> 5;
    const int q0 = wid * 32;

    const f16* kp = kb + (size_t)bh * (NKEYP * 16);
    const f16* vp = vtb + (size_t)bh * 51200;     // 25 kb * 2048
    const f16x8 bq = *(const f16x8*)(qw + ((size_t)bh * NQP + q0 + l31) * 16 + hh * 8);
    const f16* bbase = biasS + (((size_t)(h * 7 + wid) * 25) * 64 + lane) * 16;

    float mrun = -1e30f;
    float lsum = 0.f;
    f32x16 o0 = z16(), o1 = z16();

    for (int key0 = 0; key0 < NKEY; key0 += 32) {
        const int kbi = key0 >> 5;
        f16x8 ak = *(const f16x8*)(kp + (size_t)(key0 + l31) * 16 + hh * 8);
        f32x16 s = mfma32(ak, bq, z16());
        const bool tail = (key0 + 32) > NKEY;
        const f16x8* bp = (const f16x8*)(bbase + (size_t)kbi * 1024);
        f16x8 b0 = bp[0], b1 = bp[1];
        float p[16];
        float cmax = -3.0e38f;
#pragma unroll
        for (int r = 0; r < 16; ++r) {
            const int cr = (r & 3) + ((r >> 2) << 3) + (hh << 2);
            float bv = (r < 8) ? (float)b0[r] : (float)b1[r - 8];
            float sv = s[r] * SC2 + bv;
            if (tail && (key0 + cr) >= NKEY) sv = -1e30f;
            p[r] = sv;
            cmax = fmaxf(cmax, sv);
        }
        cmax = fmaxf(cmax, __shfl_xor(cmax, 32));
        if (__any(cmax > mrun + THR2)) {          // defer-max (log2 domain)
            float mnew = fmaxf(mrun, cmax);
            float f = exp2f(mrun - mnew);
            mrun = mnew;
            lsum *= f;
#pragma unroll
            for (int r = 0; r < 16; ++r) {
                const int cr = (r & 3) + ((r >> 2) << 3) + (hh << 2);
                float fr2 = __shfl(f, cr);
                o0[r] *= fr2;
                o1[r] *= fr2;
            }
        }
        float psum = 0.f;
#pragma unroll
        for (int r = 0; r < 16; ++r) {
            p[r] = exp2f(p[r] - mrun);
            psum += p[r];
        }
        lsum += psum;
        unsigned g0l = pk2(p[0], p[1]),   g0h = pk2(p[2], p[3]);
        unsigned g1l = pk2(p[4], p[5]),   g1h = pk2(p[6], p[7]);
        unsigned g2l = pk2(p[8], p[9]),   g2h = pk2(p[10], p[11]);
        unsigned g3l = pk2(p[12], p[13]), g3h = pk2(p[14], p[15]);
        __builtin_amdgcn_s_setprio(1);
        const f16* vkb = vp + (size_t)kbi * 2048;
#pragma unroll
        for (int sH = 0; sH < 2; ++sH) {
            unsigned self_lo = sH ? (hh ? g3l : g2l) : (hh ? g1l : g0l);
            unsigned self_hi = sH ? (hh ? g3h : g2h) : (hh ? g1h : g0h);
            unsigned tx_lo   = sH ? (hh ? g2l : g3l) : (hh ? g0l : g1l);
            unsigned tx_hi   = sH ? (hh ? g2h : g3h) : (hh ? g0h : g1h);
            unsigned rx_lo = __shfl_xor(tx_lo, 32);
            unsigned rx_hi = __shfl_xor(tx_hi, 32);
            uint4v w;
            w[0] = hh ? rx_lo : self_lo;
            w[1] = hh ? rx_hi : self_hi;
            w[2] = hh ? self_lo : rx_lo;
            w[3] = hh ? self_hi : rx_hi;
            f16x8 pa = __builtin_bit_cast(f16x8, w);
            const f16* vrow = vkb + sH * 1024 + l31 * 16 + hh * 8;
            f16x8 bv0 = *(const f16x8*)(vrow);
            f16x8 bv1 = *(const f16x8*)(vrow + 512);
            o0 = mfma32(pa, bv0, o0);
            o1 = mfma32(pa, bv1, o1);
        }
        __builtin_amdgcn_s_setprio(0);
    }
    lsum += __shfl_xor(lsum, 32);
    const float inv = 1.0f / lsum;
#pragma unroll
    for (int r = 0; r < 16; ++r) {
        const int cr = (r & 3) + ((r >> 2) << 3) + (hh << 2);
        const float iq = __shfl(inv, cr);
        const int qg = q0 + cr;
        if (qg < NQ) {
            float v0 = o0[r] * iq, v1 = o1[r] * iq;
            float h0 = v0 * fminf(fmaxf(v0 + 3.f, 0.f), 6.f) * (1.f / 6.f);
            float h1 = v1 * fminf(fmaxf(v1 + 3.f, 0.f), 6.f) * (1.f / 6.f);
            f16* dst = ao + ((size_t)b * NQ + qg) * 512 + h * 64 + l31;
            dst[0] = (f16)h0;
            dst[32] = (f16)h1;
        }
    }
}

// ---------------- launch ----------------
extern "C" void kernel_launch(void* const* d_in, const int* in_sizes, int n_in,
                              void* d_out, int out_size, void* d_ws, size_t ws_size,
                              hipStream_t stream) {
    (void)n_in; (void)out_size; (void)ws_size;
    const float* hidden = (const float*)d_in[0];
    const float* w_kv   = (const float*)d_in[1];
    const float* w_q    = (const float*)d_in[6];
    const float* w_p    = (const float*)d_in[11];
    const float* biases = (const float*)d_in[16];
    const int*   idxs   = (const int*)d_in[17];
    const int n_off = in_sizes[16] / 8;

    char* ws = (char*)d_ws;
    const size_t OFF_K  = 0;                       // 26,214,400
    const size_t OFF_V  = 26214400;                // 104,857,600
    const size_t OFF_Q  = 131072000;               //   7,340,032
    const size_t OFF_AO = 138412032;               //  25,690,112
    const size_t OFF_BT = 164102144;               //   2,867,200
    const size_t OFF_W  = 166969344;               //     786,432
    const size_t OFF_SC = 167755776;               //       9,216
    f16*   kbuf  = (f16*)(ws + OFF_K);
    f16*   vbuf  = (f16*)(ws + OFF_V);
    f16*   qbuf  = (f16*)(ws + OFF_Q);
    f16*   aobuf = (f16*)(ws + OFF_AO);
    f16*   btbuf = (f16*)(ws + OFF_BT);
    f16*   wf16  = (f16*)(ws + OFF_W);
    float* scbuf = (float*)(ws + OFF_SC);

    prep_scales_all<<<5, 256, 0, stream>>>(
        (const float*)d_in[2], (const float*)d_in[3], (const float*)d_in[4], (const float*)d_in[5],
        (const float*)d_in[7], (const float*)d_in[8], (const float*)d_in[9], (const float*)d_in[10],
        (const float*)d_in[12], (const float*)d_in[13], (const float*)d_in[14], (const float*)d_in[15],
        scbuf);
    conv_w<<<192, 256, 0, stream>>>(w_kv, w_q, w_p, wf16);
    prep_bias<<<5600, 256, 0, stream>>>(biases, idxs, btbuf, n_off);
    hipMemsetAsync(qbuf, 0, (size_t)1024 * NQP * 16 * 2, stream);  // zero q pad rows
    gemm_db<0><<<dim3(1568, 2), 256, 0, stream>>>(hidden, (const f16x8*)wf16, scbuf, scbuf + 640, kbuf, vbuf);
    gemm_db<1><<<dim3(392, 1), 256, 0, stream>>>(hidden, (const f16x8*)(wf16 + 163840), scbuf + 1280, scbuf + 1408, qbuf, nullptr);
    attn_fused<<<1024, 448, 0, stream>>>(kbuf, vbuf, qbuf, btbuf, aobuf);
    gemm_db<2><<<dim3(392, 2), 256, 0, stream>>>(aobuf, (const f16x8*)(wf16 + 196608), scbuf + 1536, scbuf + 1920, d_out, nullptr);
}

// Round 11
// 213.380 us; speedup vs baseline: 1.7977x; 1.0412x over previous
//
#include <hip/hip_runtime.h>

typedef _Float16 f16;
typedef __attribute__((ext_vector_type(2))) _Float16 f16x2;
typedef __attribute__((ext_vector_type(4))) _Float16 f16x4;
typedef __attribute__((ext_vector_type(8))) _Float16 f16x8;
typedef __attribute__((ext_vector_type(4))) float fvec4;
typedef __attribute__((ext_vector_type(4))) float f32x4;
typedef __attribute__((ext_vector_type(16))) float f32x16;
typedef __attribute__((ext_vector_type(4))) unsigned int uint4v;

#define NKEY 784
#define NKEYP 800
#define NQ 196
#define NQP 224
#define LOG2E 1.442695041f
#define SC2   0.360673760f   /* 0.25 * log2(e) */
#define THR2  11.5415603f    /* 8 * log2(e) */

static __device__ __forceinline__ f32x4 mfma16(f16x8 a, f16x8 b, f32x4 c) {
    return __builtin_amdgcn_mfma_f32_16x16x32_f16(a, b, c, 0, 0, 0);
}
static __device__ __forceinline__ f32x16 mfma32(f16x8 a, f16x8 b, f32x16 c) {
    return __builtin_amdgcn_mfma_f32_32x32x16_f16(a, b, c, 0, 0, 0);
}
static __device__ __forceinline__ unsigned pkrtz(float a, float b) {
    return __builtin_bit_cast(unsigned, __builtin_amdgcn_cvt_pkrtz(a, b));
}
static __device__ __forceinline__ f32x16 z16() {
    f32x16 v;
#pragma unroll
    for (int i = 0; i < 16; ++i) v[i] = 0.f;
    return v;
}

// ---------------- prep: fold BN into scale/shift (q scales also fold 0.25*log2e) ----------------
__global__ void prep_scales_all(const float* __restrict__ kg, const float* __restrict__ kb,
                                const float* __restrict__ km, const float* __restrict__ kvv,
                                const float* __restrict__ qg, const float* __restrict__ qb,
                                const float* __restrict__ qm, const float* __restrict__ qv,
                                const float* __restrict__ pg, const float* __restrict__ pb,
                                const float* __restrict__ pm, const float* __restrict__ pv,
                                float* __restrict__ sb) {
    int i = blockIdx.x * 256 + threadIdx.x;
    if (i < 640) {
        float s = kg[i] * rsqrtf(kvv[i] + 1e-5f);
        sb[i] = s; sb[640 + i] = kb[i] - km[i] * s;
    } else if (i < 768) {
        int j = i - 640;
        float s = qg[j] * rsqrtf(qv[j] + 1e-5f);
        sb[1280 + j] = s * SC2;                       // q pre-scaled: logits in log2 units
        sb[1408 + j] = (qb[j] - qm[j] * s) * SC2;
    } else if (i < 1152) {
        int j = i - 768;
        float s = pg[j] * rsqrtf(pv[j] + 1e-5f);
        sb[1536 + j] = s; sb[1920 + j] = pb[j] - pm[j] * s;
    }
}

// ---------------- prep: convert weights to f16, k-major fragment layout ----------------
__global__ void conv_w(const float* __restrict__ wkv, const float* __restrict__ wq,
                       const float* __restrict__ wp, f16* __restrict__ out) {
    int i = blockIdx.x * 256 + threadIdx.x;   // 49152 threads
    const float* src;
    f16* dst;
    int kc, n, K;
    if (i < 20480)      { int j = i;         kc = j / 640, n = j - kc * 640; src = wkv; dst = out + (size_t)j * 8;            K = 256; }
    else if (i < 24576) { int j = i - 20480; kc = j / 128, n = j - kc * 128; src = wq;  dst = out + 163840 + (size_t)j * 8;   K = 256; }
    else                { int j = i - 24576; kc = j / 384, n = j - kc * 384; src = wp;  dst = out + 196608 + (size_t)j * 8;   K = 512; }
    const float* s = src + (size_t)n * K + kc * 8;
    fvec4 v0 = *(const fvec4*)s;
    fvec4 v1 = *(const fvec4*)(s + 4);
    f16x8 h;
    h[0] = (f16)v0[0]; h[1] = (f16)v0[1]; h[2] = (f16)v0[2]; h[3] = (f16)v0[3];
    h[4] = (f16)v1[0]; h[5] = (f16)v1[1]; h[6] = (f16)v1[2]; h[7] = (f16)v1[3];
    *(f16x8*)dst = h;
}

// ---------------- prep: bias as f32 in MFMA C-operand layout, log2 domain ----------------
// biasC[h][qt(7)][kb(25)][rr(4)][lane(64)][rj(4)]; value for (q=qt*32+(lane&31),
// key=kb*32+cr) where r=rr*4+rj, cr=(r&3)+8*(r>>2)+4*(lane>>5). Key-mask folded in (-1e30).
__global__ void prep_bias(const float* __restrict__ biases, const int* __restrict__ idxs,
                          float* __restrict__ biasC, int n_off) {
    int tid = blockIdx.x * 256 + threadIdx.x;   // 1,433,600 threads
    const int rj = tid & 3;
    const int lane = (tid >> 2) & 63;
    const int rr = (tid >> 8) & 3;
    const int g = tid >> 10;                    // [h][qt][kb], 1400 groups
    const int r = rr * 4 + rj;
    const int kbk = g % 25;
    const int tmp = g / 25;
    const int qt = tmp % 7;
    const int h = tmp / 7;
    const int q = qt * 32 + (lane & 31);
    const int key = kbk * 32 + (r & 3) + 8 * (r >> 2) + 4 * (lane >> 5);
    float v;
    if (key >= NKEY)  v = -1e30f;
    else if (q < NQ)  v = biases[h * n_off + idxs[q * NKEY + key]] * LOG2E;
    else              v = 0.f;
    biasC[tid] = v;
}

// ---------------- GEMM: A in registers, W chunks double-buffered in LDS ----------------
// MODE 0: kv  : 256thr/64rows, CHUNK=32, grid(1568,2): A f32 -> K f16 [1024][800][16]
//               + V f16 [bh][kb(25)][sH(2)][d(64)][slot16] (slot = quartet-swapped key)
// MODE 1: q   : 256thr/64rows, CHUNK=32, grid(392,1)
// MODE 2: proj: 256thr/64rows, CHUNK=16 (K=512), grid(392,2)
template <int MODE>
__global__ __launch_bounds__(256) void gemm_db(
        const void* __restrict__ Ap, const f16x8* __restrict__ Wg,
        const float* __restrict__ sc, const float* __restrict__ sh,
        void* __restrict__ OutA, f16* __restrict__ OutV) {
    constexpr int K     = (MODE == 2) ? 512 : 256;
    constexpr int KS    = K / 32;
    constexpr int CHUNK = (MODE == 2) ? 16 : 32;
    constexpr int NFR   = CHUNK / 16;
    constexpr int NT    = (MODE == 0) ? 640 : (MODE == 1 ? 128 : 384);
    constexpr int NCH   = (MODE == 0) ? 10 : (MODE == 1 ? 4 : 12);
    constexpr int UNITS = (K / 8) * CHUNK;
    constexpr int SR    = UNITS / 256;

    __shared__ f16x8 Wl[2][UNITS];

    const int t = threadIdx.x;
    const int lane = t & 63, wid = t >> 6;
    const int fr = lane & 15, kg = lane >> 4;
    const int m0 = blockIdx.x * 64;
    const int nb0 = blockIdx.y * (NCH * CHUNK);
    const int mrow = m0 + wid * 16 + fr;

    size_t arow;
    if constexpr (MODE == 1) {
        int b = mrow / 196, nn = mrow - b * 196;
        arow = (size_t)b * 784 + (nn / 14) * 56 + (nn % 14) * 2;
    } else {
        arow = (size_t)mrow;
    }
    f16x8 af[KS];
#pragma unroll
    for (int ks = 0; ks < KS; ++ks) {
        if constexpr (MODE == 2) {
            af[ks] = *(const f16x8*)((const f16*)Ap + arow * K + ks * 32 + kg * 8);
        } else {
            const float* a = (const float*)Ap + arow * 256 + ks * 32 + kg * 8;
            fvec4 v0 = *(const fvec4*)a;
            fvec4 v1 = *(const fvec4*)(a + 4);
            f16x8 hv;
            hv[0] = (f16)v0[0]; hv[1] = (f16)v0[1]; hv[2] = (f16)v0[2]; hv[3] = (f16)v0[3];
            hv[4] = (f16)v1[0]; hv[5] = (f16)v1[1]; hv[6] = (f16)v1[2]; hv[7] = (f16)v1[3];
            af[ks] = hv;
        }
    }

    // ---- prologue: stage chunk 0 ----
#pragma unroll
    for (int rr = 0; rr < SR; ++rr) {
        const int idx = rr * 256 + t;
        Wl[0][idx] = Wg[(size_t)(idx / CHUNK) * NT + nb0 + (idx % CHUNK)];
    }
    __syncthreads();

    const int rg = kg * 4;
    int cur = 0;
    for (int c = 0; c < NCH; ++c) {
        const int n0c = nb0 + c * CHUNK;

        f16x8 nx0, nx1, nx2, nx3;
        if (c + 1 < NCH) {
            const int n0n = n0c + CHUNK;
            nx0 = Wg[(size_t)((0 * 256 + t) / CHUNK) * NT + n0n + ((0 * 256 + t) % CHUNK)];
            nx1 = Wg[(size_t)((1 * 256 + t) / CHUNK) * NT + n0n + ((1 * 256 + t) % CHUNK)];
            nx2 = Wg[(size_t)((2 * 256 + t) / CHUNK) * NT + n0n + ((2 * 256 + t) % CHUNK)];
            nx3 = Wg[(size_t)((3 * 256 + t) / CHUNK) * NT + n0n + ((3 * 256 + t) % CHUNK)];
        }

        f32x4 acc[NFR];
#pragma unroll
        for (int j = 0; j < NFR; ++j) acc[j] = (f32x4){0.f, 0.f, 0.f, 0.f};
#pragma unroll
        for (int ks = 0; ks < KS; ++ks) {
            f16x8 bfr[NFR];
#pragma unroll
            for (int nf = 0; nf < NFR; ++nf)
                bfr[nf] = Wl[cur][(ks * 4 + kg) * CHUNK + nf * 16 + fr];
#pragma unroll
            for (int nf = 0; nf < NFR; ++nf)
                acc[nf] = mfma16(af[ks], bfr[nf], acc[nf]);
        }

        const int mbase = m0 + wid * 16 + rg;
#pragma unroll
        for (int nf = 0; nf < NFR; ++nf) {
            const int n = n0c + nf * 16 + fr;
            const float scn = sc[n], shn = sh[n];
            if constexpr (MODE == 0) {
                const int b = mbase / 784;
                const int nn = mbase - b * 784;
                const int hd = n / 80;
                const int cc = n - hd * 80;
                const size_t bh = (size_t)(b * 8 + hd);
                if (cc < 16) {
#pragma unroll
                    for (int r = 0; r < 4; ++r) {
                        float y = acc[nf][r] * scn + shn;
                        ((f16*)OutA)[(bh * NKEYP + nn + r) * 16 + cc] = (f16)y;
                    }
                } else {
                    // V layout [bh][kb][sH][d(64)][slot16]; slot = quartet-swap of key%16
                    const int kbk = nn >> 5, sH = (nn >> 4) & 1;
                    const int kq = (nn >> 2) & 3;
                    const int slot = ((((kq & 1) << 1) | (kq >> 1)) << 2) | (nn & 3);
                    f16x4 pv;
#pragma unroll
                    for (int r = 0; r < 4; ++r) pv[r] = (f16)(acc[nf][r] * scn + shn);
                    *(f16x4*)(OutV + ((bh * 25 + kbk) * 2 + sH) * 1024 + (cc - 16) * 16 + slot) = pv;
                }
            } else if constexpr (MODE == 1) {
                const int b = mbase / 196;
                const int nn = mbase - b * 196;
                const int hd = n >> 4, cc = n & 15;
                const size_t bh = (size_t)(b * 8 + hd);
#pragma unroll
                for (int r = 0; r < 4; ++r) {
                    float y = acc[nf][r] * scn + shn;
                    ((f16*)OutA)[(bh * NQP + nn + r) * 16 + cc] = (f16)y;
                }
            } else {
#pragma unroll
                for (int r = 0; r < 4; ++r) {
                    float y = acc[nf][r] * scn + shn;
                    ((float*)OutA)[(size_t)(mbase + r) * 384 + n] = y;
                }
            }
        }

        if (c + 1 < NCH) {
            Wl[cur ^ 1][0 * 256 + t] = nx0;
            Wl[cur ^ 1][1 * 256 + t] = nx1;
            Wl[cur ^ 1][2 * 256 + t] = nx2;
            Wl[cur ^ 1][3 * 256 + t] = nx3;
            __syncthreads();
            cur ^= 1;
        }
    }
}

// ---------------- fused attention: block = (b,h), 7 waves = 7 q-tiles ----------------
// Logits come out of the QK MFMA finished (q pre-scaled, bias+mask in C operand).
// V slot-permuted so each lane's own p registers ARE the PV A-fragment (no exchange).
__global__ __launch_bounds__(448) void attn_fused(const f16* __restrict__ kb,
                                                  const f16* __restrict__ vtb,
                                                  const f16* __restrict__ qw,
                                                  const float* __restrict__ biasC,
                                                  f16* __restrict__ ao) {
    const int bh = blockIdx.x;
    const int b = bh >> 3, h = bh & 7;
    const int wid = threadIdx.x >> 6;      // q-tile 0..6
    const int lane = threadIdx.x & 63;
    const int l31 = lane & 31;
    const int hh = lane >> 5;
    const int q0 = wid * 32;

    const f16* kp = kb + (size_t)bh * (NKEYP * 16);
    const f16* vp = vtb + (size_t)bh * 51200;     // 25 kb * 2048
    const f16x8 bq = *(const f16x8*)(qw + ((size_t)bh * NQP + q0 + l31) * 16 + hh * 8);
    const float* cb = biasC + (size_t)(h * 7 + wid) * 25 * 1024 + lane * 4;

    float mrun = -1e30f;
    float lsum = 0.f;
    f32x16 o0 = z16(), o1 = z16();

    for (int kbi = 0; kbi < 25; ++kbi) {
        f16x8 ak = *(const f16x8*)(kp + (size_t)(kbi * 32 + l31) * 16 + hh * 8);
        const float* cbk = cb + kbi * 1024;
        fvec4 c0 = *(const fvec4*)(cbk);
        fvec4 c1 = *(const fvec4*)(cbk + 256);
        fvec4 c2 = *(const fvec4*)(cbk + 512);
        fvec4 c3 = *(const fvec4*)(cbk + 768);
        f32x16 ci;
        ci[0] = c0[0];  ci[1] = c0[1];  ci[2] = c0[2];  ci[3] = c0[3];
        ci[4] = c1[0];  ci[5] = c1[1];  ci[6] = c1[2];  ci[7] = c1[3];
        ci[8] = c2[0];  ci[9] = c2[1];  ci[10] = c2[2]; ci[11] = c2[3];
        ci[12] = c3[0]; ci[13] = c3[1]; ci[14] = c3[2]; ci[15] = c3[3];
        f32x16 s = mfma32(ak, bq, ci);          // finished logits (log2 units)

        float m0v = fmaxf(fmaxf(s[0], s[1]), fmaxf(s[2], s[3]));
        float m1v = fmaxf(fmaxf(s[4], s[5]), fmaxf(s[6], s[7]));
        float m2v = fmaxf(fmaxf(s[8], s[9]), fmaxf(s[10], s[11]));
        float m3v = fmaxf(fmaxf(s[12], s[13]), fmaxf(s[14], s[15]));
        float cmax = fmaxf(fmaxf(m0v, m1v), fmaxf(m2v, m3v));
        cmax = fmaxf(cmax, __shfl_xor(cmax, 32));
        if (__any(cmax > mrun + THR2)) {          // defer-max (log2 domain)
            float mnew = fmaxf(mrun, cmax);
            float f = exp2f(mrun - mnew);
            mrun = mnew;
            lsum *= f;
#pragma unroll
            for (int r = 0; r < 16; ++r) {
                const int cr = (r & 3) + ((r >> 2) << 3) + (hh << 2);
                float fr2 = __shfl(f, cr);
                o0[r] *= fr2;
                o1[r] *= fr2;
            }
        }
        float p[16];
        float psum = 0.f;
#pragma unroll
        for (int r = 0; r < 16; ++r) {
            p[r] = exp2f(s[r] - mrun);
            psum += p[r];
        }
        lsum += psum;
        uint4v w0, w1;
        w0[0] = pkrtz(p[0], p[1]);   w0[1] = pkrtz(p[2], p[3]);
        w0[2] = pkrtz(p[4], p[5]);   w0[3] = pkrtz(p[6], p[7]);
        w1[0] = pkrtz(p[8], p[9]);   w1[1] = pkrtz(p[10], p[11]);
        w1[2] = pkrtz(p[12], p[13]); w1[3] = pkrtz(p[14], p[15]);
        f16x8 pa0 = __builtin_bit_cast(f16x8, w0);   // own keys, sH=0 (slot-matched V)
        f16x8 pa1 = __builtin_bit_cast(f16x8, w1);   // own keys, sH=1
        const f16* vkb = vp + (size_t)kbi * 2048 + l31 * 16 + hh * 8;
        f16x8 bv00 = *(const f16x8*)(vkb);
        f16x8 bv01 = *(const f16x8*)(vkb + 512);
        f16x8 bv10 = *(const f16x8*)(vkb + 1024);
        f16x8 bv11 = *(const f16x8*)(vkb + 1536);
        __builtin_amdgcn_s_setprio(1);
        o0 = mfma32(pa0, bv00, o0);
        o1 = mfma32(pa0, bv01, o1);
        o0 = mfma32(pa1, bv10, o0);
        o1 = mfma32(pa1, bv11, o1);
        __builtin_amdgcn_s_setprio(0);
    }
    lsum += __shfl_xor(lsum, 32);
    const float inv = 1.0f / lsum;
#pragma unroll
    for (int r = 0; r < 16; ++r) {
        const int cr = (r & 3) + ((r >> 2) << 3) + (hh << 2);
        const float iq = __shfl(inv, cr);
        const int qg = q0 + cr;
        if (qg < NQ) {
            float v0 = o0[r] * iq, v1 = o1[r] * iq;
            float h0 = v0 * fminf(fmaxf(v0 + 3.f, 0.f), 6.f) * (1.f / 6.f);
            float h1 = v1 * fminf(fmaxf(v1 + 3.f, 0.f), 6.f) * (1.f / 6.f);
            f16* dst = ao + ((size_t)b * NQ + qg) * 512 + h * 64 + l31;
            dst[0] = (f16)h0;
            dst[32] = (f16)h1;
        }
    }
}

// ---------------- launch ----------------
extern "C" void kernel_launch(void* const* d_in, const int* in_sizes, int n_in,
                              void* d_out, int out_size, void* d_ws, size_t ws_size,
                              hipStream_t stream) {
    (void)n_in; (void)out_size;
    const float* hidden = (const float*)d_in[0];
    const float* w_kv   = (const float*)d_in[1];
    const float* w_q    = (const float*)d_in[6];
    const float* w_p    = (const float*)d_in[11];
    const float* biases = (const float*)d_in[16];
    const int*   idxs   = (const int*)d_in[17];
    const int n_off = in_sizes[16] / 8;

    char* ws = (char*)d_ws;
    const size_t OFF_K  = 0;                       //  26,214,400
    const size_t OFF_V  = 26214400;                // 104,857,600
    const size_t OFF_Q  = 131072000;               //   7,340,032
    const size_t OFF_AO = 138412032;               //  25,690,112
    const size_t OFF_W  = 164102144;               //     786,432
    const size_t OFF_SC = 164888576;               //       9,216
    const size_t OFF_BT = 164897792;               //   5,734,400 (f32 bias)
    const size_t NEED   = OFF_BT + 5734400;
    f16*   kbuf  = (f16*)(ws + OFF_K);
    f16*   vbuf  = (f16*)(ws + OFF_V);
    f16*   qbuf  = (f16*)(ws + OFF_Q);
    f16*   aobuf = (f16*)(ws + OFF_AO);
    f16*   wf16  = (f16*)(ws + OFF_W);
    float* scbuf = (float*)(ws + OFF_SC);
    // bias scratch: ws if it fits, else borrow d_out (5.7MB << 38.5MB; proj fully
    // overwrites d_out afterwards, stream-ordered, deterministic every call)
    float* btbuf = (ws_size >= NEED) ? (float*)(ws + OFF_BT) : (float*)d_out;

    prep_scales_all<<<5, 256, 0, stream>>>(
        (const float*)d_in[2], (const float*)d_in[3], (const float*)d_in[4], (const float*)d_in[5],
        (const float*)d_in[7], (const float*)d_in[8], (const float*)d_in[9], (const float*)d_in[10],
        (const float*)d_in[12], (const float*)d_in[13], (const float*)d_in[14], (const float*)d_in[15],
        scbuf);
    conv_w<<<192, 256, 0, stream>>>(w_kv, w_q, w_p, wf16);
    prep_bias<<<5600, 256, 0, stream>>>(biases, idxs, btbuf, n_off);
    hipMemsetAsync(qbuf, 0, (size_t)1024 * NQP * 16 * 2, stream);  // zero q pad rows
    gemm_db<0><<<dim3(1568, 2), 256, 0, stream>>>(hidden, (const f16x8*)wf16, scbuf, scbuf + 640, kbuf, vbuf);
    gemm_db<1><<<dim3(392, 1), 256, 0, stream>>>(hidden, (const f16x8*)(wf16 + 163840), scbuf + 1280, scbuf + 1408, qbuf, nullptr);
    attn_fused<<<1024, 448, 0, stream>>>(kbuf, vbuf, qbuf, btbuf, aobuf);
    gemm_db<2><<<dim3(392, 2), 256, 0, stream>>>(aobuf, (const f16x8*)(wf16 + 196608), scbuf + 1536, scbuf + 1920, d_out, nullptr);
}

// Round 12
// 207.001 us; speedup vs baseline: 1.8531x; 1.0308x over previous
//
#include <hip/hip_runtime.h>

typedef _Float16 f16;
typedef __attribute__((ext_vector_type(2))) _Float16 f16x2;
typedef __attribute__((ext_vector_type(4))) _Float16 f16x4;
typedef __attribute__((ext_vector_type(8))) _Float16 f16x8;
typedef __attribute__((ext_vector_type(4))) float fvec4;
typedef __attribute__((ext_vector_type(4))) float f32x4;
typedef __attribute__((ext_vector_type(16))) float f32x16;
typedef __attribute__((ext_vector_type(4))) unsigned int uint4v;

#define NKEY 784
#define NKEYP 800
#define NQ 196
#define NQP 224
#define LOG2E 1.442695041f
#define SC2   0.360673760f   /* 0.25 * log2(e) */
#define THR2  11.5415603f    /* 8 * log2(e) */

static __device__ __forceinline__ f32x4 mfma16(f16x8 a, f16x8 b, f32x4 c) {
    return __builtin_amdgcn_mfma_f32_16x16x32_f16(a, b, c, 0, 0, 0);
}
static __device__ __forceinline__ f32x16 mfma32(f16x8 a, f16x8 b, f32x16 c) {
    return __builtin_amdgcn_mfma_f32_32x32x16_f16(a, b, c, 0, 0, 0);
}
static __device__ __forceinline__ unsigned pkrtz(float a, float b) {
    return __builtin_bit_cast(unsigned, __builtin_amdgcn_cvt_pkrtz(a, b));
}
static __device__ __forceinline__ f32x16 z16() {
    f32x16 v;
#pragma unroll
    for (int i = 0; i < 16; ++i) v[i] = 0.f;
    return v;
}

// ---------------- prep: fold BN into scale/shift (q scales also fold 0.25*log2e) ----------------
__global__ void prep_scales_all(const float* __restrict__ kg, const float* __restrict__ kb,
                                const float* __restrict__ km, const float* __restrict__ kvv,
                                const float* __restrict__ qg, const float* __restrict__ qb,
                                const float* __restrict__ qm, const float* __restrict__ qv,
                                const float* __restrict__ pg, const float* __restrict__ pb,
                                const float* __restrict__ pm, const float* __restrict__ pv,
                                float* __restrict__ sb) {
    int i = blockIdx.x * 256 + threadIdx.x;
    if (i < 640) {
        float s = kg[i] * rsqrtf(kvv[i] + 1e-5f);
        sb[i] = s; sb[640 + i] = kb[i] - km[i] * s;
    } else if (i < 768) {
        int j = i - 640;
        float s = qg[j] * rsqrtf(qv[j] + 1e-5f);
        sb[1280 + j] = s * SC2;                       // q pre-scaled: logits in log2 units
        sb[1408 + j] = (qb[j] - qm[j] * s) * SC2;
    } else if (i < 1152) {
        int j = i - 768;
        float s = pg[j] * rsqrtf(pv[j] + 1e-5f);
        sb[1536 + j] = s; sb[1920 + j] = pb[j] - pm[j] * s;
    }
}

// ---------------- prep: convert weights to f16, k-major fragment layout ----------------
__global__ void conv_w(const float* __restrict__ wkv, const float* __restrict__ wq,
                       const float* __restrict__ wp, f16* __restrict__ out) {
    int i = blockIdx.x * 256 + threadIdx.x;   // 49152 threads
    const float* src;
    f16* dst;
    int kc, n, K;
    if (i < 20480)      { int j = i;         kc = j / 640, n = j - kc * 640; src = wkv; dst = out + (size_t)j * 8;            K = 256; }
    else if (i < 24576) { int j = i - 20480; kc = j / 128, n = j - kc * 128; src = wq;  dst = out + 163840 + (size_t)j * 8;   K = 256; }
    else                { int j = i - 24576; kc = j / 384, n = j - kc * 384; src = wp;  dst = out + 196608 + (size_t)j * 8;   K = 512; }
    const float* s = src + (size_t)n * K + kc * 8;
    fvec4 v0 = *(const fvec4*)s;
    fvec4 v1 = *(const fvec4*)(s + 4);
    f16x8 h;
    h[0] = (f16)v0[0]; h[1] = (f16)v0[1]; h[2] = (f16)v0[2]; h[3] = (f16)v0[3];
    h[4] = (f16)v1[0]; h[5] = (f16)v1[1]; h[6] = (f16)v1[2]; h[7] = (f16)v1[3];
    *(f16x8*)dst = h;
}

// ---------------- prep: bias as f32 in MFMA C-operand layout, log2 domain ----------------
// biasC[h][qt(7)][kb(25)][rr(4)][lane(64)][rj(4)]; value for (q=qt*32+(lane&31),
// key=kb*32+cr) where r=rr*4+rj, cr=(r&3)+8*(r>>2)+4*(lane>>5). Key-mask folded in (-1e30).
__global__ void prep_bias(const float* __restrict__ biases, const int* __restrict__ idxs,
                          float* __restrict__ biasC, int n_off) {
    int tid = blockIdx.x * 256 + threadIdx.x;   // 1,433,600 threads
    const int rj = tid & 3;
    const int lane = (tid >> 2) & 63;
    const int rr = (tid >> 8) & 3;
    const int g = tid >> 10;                    // [h][qt][kb], 1400 groups
    const int r = rr * 4 + rj;
    const int kbk = g % 25;
    const int tmp = g / 25;
    const int qt = tmp % 7;
    const int h = tmp / 7;
    const int q = qt * 32 + (lane & 31);
    const int key = kbk * 32 + (r & 3) + 8 * (r >> 2) + 4 * (lane >> 5);
    float v;
    if (key >= NKEY)  v = -1e30f;
    else if (q < NQ)  v = biases[h * n_off + idxs[q * NKEY + key]] * LOG2E;
    else              v = 0.f;
    biasC[tid] = v;
}

// ---------------- GEMM: A in registers, W chunks double-buffered in LDS ----------------
// MODE 0: kv  : 256thr/64rows, CHUNK=32, NCH=20, grid(1568,1): A read ONCE
//               -> K f16 [1024][800][16]
//               + V f16 [bh][kb(25)][sH(2)][d(64)][slot16] (slot = quartet-swapped key)
// MODE 1: q   : 256thr/64rows, CHUNK=32, grid(392,1)
// MODE 2: proj: 256thr/64rows, CHUNK=16 (K=512), grid(392,2)
template <int MODE>
__global__ __launch_bounds__(256) void gemm_db(
        const void* __restrict__ Ap, const f16x8* __restrict__ Wg,
        const float* __restrict__ sc, const float* __restrict__ sh,
        void* __restrict__ OutA, f16* __restrict__ OutV) {
    constexpr int K     = (MODE == 2) ? 512 : 256;
    constexpr int KS    = K / 32;
    constexpr int CHUNK = (MODE == 2) ? 16 : 32;
    constexpr int NFR   = CHUNK / 16;
    constexpr int NT    = (MODE == 0) ? 640 : (MODE == 1 ? 128 : 384);
    constexpr int NCH   = (MODE == 0) ? 20 : (MODE == 1 ? 4 : 12);
    constexpr int UNITS = (K / 8) * CHUNK;
    constexpr int SR    = UNITS / 256;

    __shared__ f16x8 Wl[2][UNITS];

    const int t = threadIdx.x;
    const int lane = t & 63, wid = t >> 6;
    const int fr = lane & 15, kg = lane >> 4;
    const int m0 = blockIdx.x * 64;
    const int nb0 = blockIdx.y * (NCH * CHUNK);
    const int mrow = m0 + wid * 16 + fr;

    size_t arow;
    if constexpr (MODE == 1) {
        int b = mrow / 196, nn = mrow - b * 196;
        arow = (size_t)b * 784 + (nn / 14) * 56 + (nn % 14) * 2;
    } else {
        arow = (size_t)mrow;
    }
    f16x8 af[KS];
#pragma unroll
    for (int ks = 0; ks < KS; ++ks) {
        if constexpr (MODE == 2) {
            af[ks] = *(const f16x8*)((const f16*)Ap + arow * K + ks * 32 + kg * 8);
        } else {
            const float* a = (const float*)Ap + arow * 256 + ks * 32 + kg * 8;
            fvec4 v0 = *(const fvec4*)a;
            fvec4 v1 = *(const fvec4*)(a + 4);
            f16x8 hv;
            hv[0] = (f16)v0[0]; hv[1] = (f16)v0[1]; hv[2] = (f16)v0[2]; hv[3] = (f16)v0[3];
            hv[4] = (f16)v1[0]; hv[5] = (f16)v1[1]; hv[6] = (f16)v1[2]; hv[7] = (f16)v1[3];
            af[ks] = hv;
        }
    }

    // ---- prologue: stage chunk 0 ----
#pragma unroll
    for (int rr = 0; rr < SR; ++rr) {
        const int idx = rr * 256 + t;
        Wl[0][idx] = Wg[(size_t)(idx / CHUNK) * NT + nb0 + (idx % CHUNK)];
    }
    __syncthreads();

    const int rg = kg * 4;
    int cur = 0;
    for (int c = 0; c < NCH; ++c) {
        const int n0c = nb0 + c * CHUNK;

        f16x8 nx0, nx1, nx2, nx3;
        if (c + 1 < NCH) {
            const int n0n = n0c + CHUNK;
            nx0 = Wg[(size_t)((0 * 256 + t) / CHUNK) * NT + n0n + ((0 * 256 + t) % CHUNK)];
            nx1 = Wg[(size_t)((1 * 256 + t) / CHUNK) * NT + n0n + ((1 * 256 + t) % CHUNK)];
            if constexpr (SR > 2) {
                nx2 = Wg[(size_t)((2 * 256 + t) / CHUNK) * NT + n0n + ((2 * 256 + t) % CHUNK)];
                nx3 = Wg[(size_t)((3 * 256 + t) / CHUNK) * NT + n0n + ((3 * 256 + t) % CHUNK)];
            }
        }

        f32x4 acc[NFR];
#pragma unroll
        for (int j = 0; j < NFR; ++j) acc[j] = (f32x4){0.f, 0.f, 0.f, 0.f};
#pragma unroll
        for (int ks = 0; ks < KS; ++ks) {
            f16x8 bfr[NFR];
#pragma unroll
            for (int nf = 0; nf < NFR; ++nf)
                bfr[nf] = Wl[cur][(ks * 4 + kg) * CHUNK + nf * 16 + fr];
#pragma unroll
            for (int nf = 0; nf < NFR; ++nf)
                acc[nf] = mfma16(af[ks], bfr[nf], acc[nf]);
        }

        const int mbase = m0 + wid * 16 + rg;
#pragma unroll
        for (int nf = 0; nf < NFR; ++nf) {
            const int n = n0c + nf * 16 + fr;
            const float scn = sc[n], shn = sh[n];
            if constexpr (MODE == 0) {
                const int b = mbase / 784;
                const int nn = mbase - b * 784;
                const int hd = n / 80;
                const int cc = n - hd * 80;
                const size_t bh = (size_t)(b * 8 + hd);
                if (cc < 16) {
#pragma unroll
                    for (int r = 0; r < 4; ++r) {
                        float y = acc[nf][r] * scn + shn;
                        ((f16*)OutA)[(bh * NKEYP + nn + r) * 16 + cc] = (f16)y;
                    }
                } else {
                    // V layout [bh][kb][sH][d(64)][slot16]; slot = quartet-swap of key%16
                    const int kbk = nn >> 5, sH = (nn >> 4) & 1;
                    const int kq = (nn >> 2) & 3;
                    const int slot = ((((kq & 1) << 1) | (kq >> 1)) << 2) | (nn & 3);
                    f16x4 pv;
#pragma unroll
                    for (int r = 0; r < 4; ++r) pv[r] = (f16)(acc[nf][r] * scn + shn);
                    *(f16x4*)(OutV + ((bh * 25 + kbk) * 2 + sH) * 1024 + (cc - 16) * 16 + slot) = pv;
                }
            } else if constexpr (MODE == 1) {
                const int b = mbase / 196;
                const int nn = mbase - b * 196;
                const int hd = n >> 4, cc = n & 15;
                const size_t bh = (size_t)(b * 8 + hd);
#pragma unroll
                for (int r = 0; r < 4; ++r) {
                    float y = acc[nf][r] * scn + shn;
                    ((f16*)OutA)[(bh * NQP + nn + r) * 16 + cc] = (f16)y;
                }
            } else {
#pragma unroll
                for (int r = 0; r < 4; ++r) {
                    float y = acc[nf][r] * scn + shn;
                    ((float*)OutA)[(size_t)(mbase + r) * 384 + n] = y;
                }
            }
        }

        if (c + 1 < NCH) {
            Wl[cur ^ 1][0 * 256 + t] = nx0;
            Wl[cur ^ 1][1 * 256 + t] = nx1;
            if constexpr (SR > 2) {
                Wl[cur ^ 1][2 * 256 + t] = nx2;
                Wl[cur ^ 1][3 * 256 + t] = nx3;
            }
            __syncthreads();
            cur ^= 1;
        }
    }
}

// ---------------- fused attention: block = (b,h), 7 waves = 7 q-tiles ----------------
// Logits finished by the QK MFMA (q pre-scaled, bias+mask in C operand); V slot-permuted
// so each lane's own p registers are the PV A-fragment. Pointer-bump addressing.
__global__ __launch_bounds__(448) void attn_fused(const f16* __restrict__ kb,
                                                  const f16* __restrict__ vtb,
                                                  const f16* __restrict__ qw,
                                                  const float* __restrict__ biasC,
                                                  f16* __restrict__ ao) {
    const int bh = blockIdx.x;
    const int b = bh >> 3, h = bh & 7;
    const int wid = threadIdx.x >> 6;      // q-tile 0..6
    const int lane = threadIdx.x & 63;
    const int l31 = lane & 31;
    const int hh = lane >> 5;
    const int q0 = wid * 32;

    const f16x8 bq = *(const f16x8*)(qw + ((size_t)bh * NQP + q0 + l31) * 16 + hh * 8);
    const f16*   kpp = kb + (size_t)bh * (NKEYP * 16) + (size_t)l31 * 16 + hh * 8;
    const float* cbp = biasC + (size_t)(h * 7 + wid) * 25 * 1024 + lane * 4;
    const f16*   vkb = vtb + (size_t)bh * 51200 + l31 * 16 + hh * 8;

    float mrun = -1e30f;
    float lsum = 0.f;
    f32x16 o0 = z16(), o1 = z16();

    for (int kbi = 0; kbi < 25; ++kbi, kpp += 512, cbp += 1024, vkb += 2048) {
        f16x8 ak = *(const f16x8*)kpp;
        fvec4 c0 = *(const fvec4*)(cbp);
        fvec4 c1 = *(const fvec4*)(cbp + 256);
        fvec4 c2 = *(const fvec4*)(cbp + 512);
        fvec4 c3 = *(const fvec4*)(cbp + 768);
        f32x16 ci;
        ci[0] = c0[0];  ci[1] = c0[1];  ci[2] = c0[2];  ci[3] = c0[3];
        ci[4] = c1[0];  ci[5] = c1[1];  ci[6] = c1[2];  ci[7] = c1[3];
        ci[8] = c2[0];  ci[9] = c2[1];  ci[10] = c2[2]; ci[11] = c2[3];
        ci[12] = c3[0]; ci[13] = c3[1]; ci[14] = c3[2]; ci[15] = c3[3];
        f32x16 s = mfma32(ak, bq, ci);          // finished logits (log2 units)

        float m0v = fmaxf(fmaxf(s[0], s[1]), fmaxf(s[2], s[3]));
        float m1v = fmaxf(fmaxf(s[4], s[5]), fmaxf(s[6], s[7]));
        float m2v = fmaxf(fmaxf(s[8], s[9]), fmaxf(s[10], s[11]));
        float m3v = fmaxf(fmaxf(s[12], s[13]), fmaxf(s[14], s[15]));
        float cmax = fmaxf(fmaxf(m0v, m1v), fmaxf(m2v, m3v));
        cmax = fmaxf(cmax, __shfl_xor(cmax, 32));
        if (__any(cmax > mrun + THR2)) {          // defer-max (log2 domain)
            float mnew = fmaxf(mrun, cmax);
            float f = exp2f(mrun - mnew);
            mrun = mnew;
            lsum *= f;
#pragma unroll
            for (int r = 0; r < 16; ++r) {
                const int cr = (r & 3) + ((r >> 2) << 3) + (hh << 2);
                float fr2 = __shfl(f, cr);
                o0[r] *= fr2;
                o1[r] *= fr2;
            }
        }
        float p[16];
        float psum = 0.f;
#pragma unroll
        for (int r = 0; r < 16; ++r) {
            p[r] = exp2f(s[r] - mrun);
            psum += p[r];
        }
        lsum += psum;
        uint4v w0, w1;
        w0[0] = pkrtz(p[0], p[1]);   w0[1] = pkrtz(p[2], p[3]);
        w0[2] = pkrtz(p[4], p[5]);   w0[3] = pkrtz(p[6], p[7]);
        w1[0] = pkrtz(p[8], p[9]);   w1[1] = pkrtz(p[10], p[11]);
        w1[2] = pkrtz(p[12], p[13]); w1[3] = pkrtz(p[14], p[15]);
        f16x8 pa0 = __builtin_bit_cast(f16x8, w0);   // own keys, sH=0 (slot-matched V)
        f16x8 pa1 = __builtin_bit_cast(f16x8, w1);   // own keys, sH=1
        f16x8 bv00 = *(const f16x8*)(vkb);
        f16x8 bv01 = *(const f16x8*)(vkb + 512);
        f16x8 bv10 = *(const f16x8*)(vkb + 1024);
        f16x8 bv11 = *(const f16x8*)(vkb + 1536);
        __builtin_amdgcn_s_setprio(1);
        o0 = mfma32(pa0, bv00, o0);
        o1 = mfma32(pa0, bv01, o1);
        o0 = mfma32(pa1, bv10, o0);
        o1 = mfma32(pa1, bv11, o1);
        __builtin_amdgcn_s_setprio(0);
    }
    lsum += __shfl_xor(lsum, 32);
    const float inv = 1.0f / lsum;
#pragma unroll
    for (int r = 0; r < 16; ++r) {
        const int cr = (r & 3) + ((r >> 2) << 3) + (hh << 2);
        const float iq = __shfl(inv, cr);
        const int qg = q0 + cr;
        if (qg < NQ) {
            float v0 = o0[r] * iq, v1 = o1[r] * iq;
            float h0 = v0 * fminf(fmaxf(v0 + 3.f, 0.f), 6.f) * (1.f / 6.f);
            float h1 = v1 * fminf(fmaxf(v1 + 3.f, 0.f), 6.f) * (1.f / 6.f);
            f16* dst = ao + ((size_t)b * NQ + qg) * 512 + h * 64 + l31;
            dst[0] = (f16)h0;
            dst[32] = (f16)h1;
        }
    }
}

// ---------------- launch ----------------
extern "C" void kernel_launch(void* const* d_in, const int* in_sizes, int n_in,
                              void* d_out, int out_size, void* d_ws, size_t ws_size,
                              hipStream_t stream) {
    (void)n_in; (void)out_size;
    const float* hidden = (const float*)d_in[0];
    const float* w_kv   = (const float*)d_in[1];
    const float* w_q    = (const float*)d_in[6];
    const float* w_p    = (const float*)d_in[11];
    const float* biases = (const float*)d_in[16];
    const int*   idxs   = (const int*)d_in[17];
    const int n_off = in_sizes[16] / 8;

    char* ws = (char*)d_ws;
    const size_t OFF_K  = 0;                       //  26,214,400
    const size_t OFF_V  = 26214400;                // 104,857,600
    const size_t OFF_Q  = 131072000;               //   7,340,032
    const size_t OFF_AO = 138412032;               //  25,690,112
    const size_t OFF_W  = 164102144;               //     786,432
    const size_t OFF_SC = 164888576;               //       9,216
    const size_t OFF_BT = 164897792;               //   5,734,400 (f32 bias)
    const size_t NEED   = OFF_BT + 5734400;
    f16*   kbuf  = (f16*)(ws + OFF_K);
    f16*   vbuf  = (f16*)(ws + OFF_V);
    f16*   qbuf  = (f16*)(ws + OFF_Q);
    f16*   aobuf = (f16*)(ws + OFF_AO);
    f16*   wf16  = (f16*)(ws + OFF_W);
    float* scbuf = (float*)(ws + OFF_SC);
    // bias scratch: ws if it fits, else borrow d_out (proj fully overwrites it later,
    // stream-ordered, deterministic every call)
    float* btbuf = (ws_size >= NEED) ? (float*)(ws + OFF_BT) : (float*)d_out;

    prep_scales_all<<<5, 256, 0, stream>>>(
        (const float*)d_in[2], (const float*)d_in[3], (const float*)d_in[4], (const float*)d_in[5],
        (const float*)d_in[7], (const float*)d_in[8], (const float*)d_in[9], (const float*)d_in[10],
        (const float*)d_in[12], (const float*)d_in[13], (const float*)d_in[14], (const float*)d_in[15],
        scbuf);
    conv_w<<<192, 256, 0, stream>>>(w_kv, w_q, w_p, wf16);
    prep_bias<<<5600, 256, 0, stream>>>(biases, idxs, btbuf, n_off);
    hipMemsetAsync(qbuf, 0, (size_t)1024 * NQP * 16 * 2, stream);  // zero q pad rows
    gemm_db<0><<<dim3(1568, 1), 256, 0, stream>>>(hidden, (const f16x8*)wf16, scbuf, scbuf + 640, kbuf, vbuf);
    gemm_db<1><<<dim3(392, 1), 256, 0, stream>>>(hidden, (const f16x8*)(wf16 + 163840), scbuf + 1280, scbuf + 1408, qbuf, nullptr);
    attn_fused<<<1024, 448, 0, stream>>>(kbuf, vbuf, qbuf, btbuf, aobuf);
    gemm_db<2><<<dim3(392, 2), 256, 0, stream>>>(aobuf, (const f16x8*)(wf16 + 196608), scbuf + 1536, scbuf + 1920, d_out, nullptr);
}